// Round 1
// baseline (587.210 us; speedup 1.0000x reference)
//
#include <hip/hip_runtime.h>
#include <hip/hip_bf16.h>

#define NB 4
#define NT 2048
#define ND 1024
#define NH 16
#define NHD 64
#define NF 4096
#define MTOK (NB*NT)  // 8192

typedef float f32x4 __attribute__((ext_vector_type(4)));
typedef __bf16 bf16x8 __attribute__((ext_vector_type(8)));
typedef short s16x8 __attribute__((ext_vector_type(8)));
typedef unsigned short ushort_t;

__device__ inline ushort_t f2bf(float f) {
    unsigned int u = __builtin_bit_cast(unsigned int, f);
    unsigned int r = (u + 0x7FFFu + ((u >> 16) & 1u)) >> 16;
    return (ushort_t)r;
}

// ---------------------------------------------------------------------------
// Transpose-convert: src fp32 (R x C) row-major -> dst bf16 (C x R) row-major
// ---------------------------------------------------------------------------
__global__ __launch_bounds__(256)
void transpose_to_bf16(const float* __restrict__ src, ushort_t* __restrict__ dst,
                       int R, int C) {
    __shared__ float tile[32][33];
    int c0 = blockIdx.x * 32, r0 = blockIdx.y * 32;
    #pragma unroll
    for (int i = 0; i < 32; i += 8)
        tile[threadIdx.y + i][threadIdx.x] =
            src[(size_t)(r0 + threadIdx.y + i) * C + c0 + threadIdx.x];
    __syncthreads();
    #pragma unroll
    for (int i = 0; i < 32; i += 8)
        dst[(size_t)(c0 + threadIdx.y + i) * R + r0 + threadIdx.x] =
            f2bf(tile[threadIdx.x][threadIdx.y + i]);
}

// QKV weights: Wq/Wk/Wv are (H, D, HD). Build Bt (3072 x 1024) bf16 where
// row n = w*1024 + h*64 + j holds W_w[h][:, j] (K index = d).
__global__ __launch_bounds__(256)
void transpose_qkv_to_bf16(const float* __restrict__ Wq, const float* __restrict__ Wk,
                           const float* __restrict__ Wv, ushort_t* __restrict__ dst) {
    __shared__ float tile[32][33];
    int z = blockIdx.z;            // 0..47
    int w = z >> 4, h = z & 15;
    const float* src = (w == 0 ? Wq : (w == 1 ? Wk : Wv)) + (size_t)h * ND * NHD;
    ushort_t* out = dst + ((size_t)w * ND + h * NHD) * ND;
    int c0 = blockIdx.x * 32, r0 = blockIdx.y * 32;  // C=64 (j), R=1024 (d)
    #pragma unroll
    for (int i = 0; i < 32; i += 8)
        tile[threadIdx.y + i][threadIdx.x] =
            src[(size_t)(r0 + threadIdx.y + i) * NHD + c0 + threadIdx.x];
    __syncthreads();
    #pragma unroll
    for (int i = 0; i < 32; i += 8)
        out[(size_t)(c0 + threadIdx.y + i) * ND + r0 + threadIdx.x] =
            f2bf(tile[threadIdx.x][threadIdx.y + i]);
}

// ---------------------------------------------------------------------------
// LayerNorm (rows of 1024 fp32) -> bf16 out
// ---------------------------------------------------------------------------
__global__ __launch_bounds__(256)
void layernorm_to_bf16(const float* __restrict__ x, const float* __restrict__ g,
                       const float* __restrict__ bvec, ushort_t* __restrict__ out) {
    int row = blockIdx.x;
    const float4* xr = (const float4*)(x + (size_t)row * ND);
    float4 v = xr[threadIdx.x];
    float s = v.x + v.y + v.z + v.w;
    float s2 = v.x * v.x + v.y * v.y + v.z * v.z + v.w * v.w;
    #pragma unroll
    for (int o = 32; o >= 1; o >>= 1) {
        s += __shfl_xor(s, o);
        s2 += __shfl_xor(s2, o);
    }
    __shared__ float red[8];
    int wave = threadIdx.x >> 6, lane = threadIdx.x & 63;
    if (lane == 0) { red[wave] = s; red[4 + wave] = s2; }
    __syncthreads();
    float ts = red[0] + red[1] + red[2] + red[3];
    float ts2 = red[4] + red[5] + red[6] + red[7];
    float mu = ts * (1.f / ND);
    float var = ts2 * (1.f / ND) - mu * mu;
    float rs = rsqrtf(var + 1e-5f);
    float4 gv = ((const float4*)g)[threadIdx.x];
    float4 bv = ((const float4*)bvec)[threadIdx.x];
    ushort4 o4;
    o4.x = f2bf((v.x - mu) * rs * gv.x + bv.x);
    o4.y = f2bf((v.y - mu) * rs * gv.y + bv.y);
    o4.z = f2bf((v.z - mu) * rs * gv.z + bv.z);
    o4.w = f2bf((v.w - mu) * rs * gv.w + bv.w);
    ((ushort4*)(out + (size_t)row * ND))[threadIdx.x] = o4;
}

// ---------------------------------------------------------------------------
// GEMM: C[M,N] = A[M,K] (bf16) * Bt[N,K]^T (bf16)  (+bias, relu, +res) -> f32/bf16
// 128x128 tile, BK=64, 4 waves, mfma 16x16x32, XOR-swizzled LDS.
// ---------------------------------------------------------------------------
template<bool HAS_BIAS, bool RELU, bool HAS_RES, bool OUT_F32>
__global__ __launch_bounds__(256)
void gemm_bf16(const ushort_t* __restrict__ A, const ushort_t* __restrict__ Bt,
               const float* __restrict__ bias, const float* __restrict__ res,
               void* __restrict__ outp, int M, int N, int K) {
    __shared__ __align__(16) ushort_t As[128 * 64];
    __shared__ __align__(16) ushort_t Bs[128 * 64];
    const int t = threadIdx.x;
    const int wave = t >> 6, lane = t & 63;
    const int m0 = blockIdx.y * 128, n0 = blockIdx.x * 128;
    const int wr = (wave >> 1) * 64, wc = (wave & 1) * 64;
    const int srow = t >> 3;           // 0..31
    const int scol = (t & 7) * 8;      // 0..56
    f32x4 acc[4][4] = {};

    for (int kt = 0; kt < K; kt += 64) {
        bf16x8 av[4], bv[4];
        #pragma unroll
        for (int c = 0; c < 4; c++) {
            int row = srow + c * 32;
            av[c] = *(const bf16x8*)(A + (size_t)(m0 + row) * K + kt + scol);
            bv[c] = *(const bf16x8*)(Bt + (size_t)(n0 + row) * K + kt + scol);
        }
        __syncthreads();
        #pragma unroll
        for (int c = 0; c < 4; c++) {
            int row = srow + c * 32;
            int a = row * 128 + scol * 2;
            a ^= ((row & 7) << 4);
            *(bf16x8*)((char*)As + a) = av[c];
            *(bf16x8*)((char*)Bs + a) = bv[c];
        }
        __syncthreads();
        #pragma unroll
        for (int ks = 0; ks < 2; ks++) {
            bf16x8 af[4], bfr[4];
            #pragma unroll
            for (int m = 0; m < 4; m++) {
                int row = wr + m * 16 + (lane & 15);
                int a = row * 128 + (ks * 32 + 8 * (lane >> 4)) * 2;
                a ^= ((row & 7) << 4);
                af[m] = *(const bf16x8*)((const char*)As + a);
            }
            #pragma unroll
            for (int n = 0; n < 4; n++) {
                int row = wc + n * 16 + (lane & 15);
                int a = row * 128 + (ks * 32 + 8 * (lane >> 4)) * 2;
                a ^= ((row & 7) << 4);
                bfr[n] = *(const bf16x8*)((const char*)Bs + a);
            }
            #pragma unroll
            for (int m = 0; m < 4; m++)
                #pragma unroll
                for (int n = 0; n < 4; n++)
                    acc[m][n] = __builtin_amdgcn_mfma_f32_16x16x32_bf16(
                        af[m], bfr[n], acc[m][n], 0, 0, 0);
        }
    }

    const int gr0 = m0 + wr + (lane >> 4) * 4;
    const int gc0 = n0 + wc + (lane & 15);
    #pragma unroll
    for (int mf = 0; mf < 4; mf++) {
        #pragma unroll
        for (int nf = 0; nf < 4; nf++) {
            int col = gc0 + nf * 16;
            float bb = 0.f;
            if constexpr (HAS_BIAS) bb = bias[col];
            #pragma unroll
            for (int r = 0; r < 4; r++) {
                int row = gr0 + mf * 16 + r;
                float v = acc[mf][nf][r] + bb;
                if constexpr (RELU) v = fmaxf(v, 0.f);
                if constexpr (HAS_RES) v += res[(size_t)row * N + col];
                if constexpr (OUT_F32)
                    ((float*)outp)[(size_t)row * N + col] = v;
                else
                    ((ushort_t*)outp)[(size_t)row * N + col] = f2bf(v);
            }
        }
    }
}

// ---------------------------------------------------------------------------
// Causal flash attention. qkv: (8192 x 3072) bf16, cols [q|k|v], each col
// block = h*64+j. One block per (q-tile of 64, b*h). 4 waves x 16 q-rows.
// ---------------------------------------------------------------------------
__global__ __launch_bounds__(256)
void attn_kernel(const ushort_t* __restrict__ qkv, ushort_t* __restrict__ out) {
    __shared__ __align__(16) ushort_t Ks[64][72];
    __shared__ __align__(16) ushort_t Vt[64 * 64];   // swizzled, d-major
    __shared__ __align__(16) ushort_t Pl[4][16][72];
    const int qt = blockIdx.x, bh = blockIdx.y;
    const int b = bh >> 4, h = bh & 15;
    const int t = threadIdx.x, wave = t >> 6, lane = t & 63;
    const int q0 = qt * 64;
    const size_t base = ((size_t)b * NT) * 3072 + h * NHD;
    const ushort_t* qb = qkv + base;
    const ushort_t* kb = qkv + base + 1024;
    const ushort_t* vb = qkv + base + 2048;

    bf16x8 qf[2];
    {
        const int qrow = q0 + wave * 16 + (lane & 15);
        const ushort_t* qp = qb + (size_t)qrow * 3072 + 8 * (lane >> 4);
        qf[0] = *(const bf16x8*)qp;
        qf[1] = *(const bf16x8*)(qp + 32);
    }
    f32x4 of[4] = {};
    float m_run[4], l_run[4];
    #pragma unroll
    for (int r = 0; r < 4; r++) { m_run[r] = -__builtin_inff(); l_run[r] = 0.f; }

    const int srow = t >> 3, scolg = t & 7;

    for (int kv = 0; kv <= qt; ++kv) {
        __syncthreads();
        // stage K tile (64 keys x 64 dims), row-major
        #pragma unroll
        for (int c = 0; c < 2; c++) {
            int row = srow + c * 32;
            *(bf16x8*)&Ks[row][scolg * 8] =
                *(const bf16x8*)(kb + (size_t)(kv * 64 + row) * 3072 + scolg * 8);
        }
        // stage V tile transposed (d-major), XOR-swizzled for conflict-free r/w
        {
            const ushort_t* vp = vb + (size_t)(kv * 64 + 2 * srow) * 3072 + scolg * 8;
            s16x8 v0 = *(const s16x8*)vp;
            s16x8 v1 = *(const s16x8*)(vp + 3072);
            #pragma unroll
            for (int dd = 0; dd < 8; dd++) {
                int d = scolg * 8 + dd;
                unsigned int wv = (unsigned int)(ushort_t)v0[dd] |
                                  ((unsigned int)(ushort_t)v1[dd] << 16);
                int a = (d << 7) + (srow << 2);
                a ^= (((d & 7) ^ ((d >> 3) & 7)) << 4);
                *(unsigned int*)((char*)Vt + a) = wv;
            }
        }
        __syncthreads();

        // S = Q K^T
        f32x4 sf[4] = {};
        #pragma unroll
        for (int n = 0; n < 4; n++) {
            #pragma unroll
            for (int kd = 0; kd < 2; kd++) {
                bf16x8 kf = *(const bf16x8*)&Ks[n * 16 + (lane & 15)][kd * 32 + 8 * (lane >> 4)];
                sf[n] = __builtin_amdgcn_mfma_f32_16x16x32_bf16(qf[kd], kf, sf[n], 0, 0, 0);
            }
        }
        // online softmax
        float sc[4][4];
        float pm[4];
        #pragma unroll
        for (int r = 0; r < 4; r++) pm[r] = -__builtin_inff();
        const bool diag = (kv == qt);
        #pragma unroll
        for (int n = 0; n < 4; n++) {
            #pragma unroll
            for (int r = 0; r < 4; r++) {
                float v = sf[n][r] * 0.03125f;
                if (diag) {
                    int jg = kv * 64 + n * 16 + (lane & 15);
                    int qg = q0 + wave * 16 + (lane >> 4) * 4 + r;
                    if (jg > qg) v = -__builtin_inff();
                }
                sc[n][r] = v;
                pm[r] = fmaxf(pm[r], v);
            }
        }
        #pragma unroll
        for (int r = 0; r < 4; r++) {
            #pragma unroll
            for (int o = 8; o >= 1; o >>= 1) pm[r] = fmaxf(pm[r], __shfl_xor(pm[r], o));
        }
        float corr[4], ps[4];
        #pragma unroll
        for (int r = 0; r < 4; r++) {
            float mn = fmaxf(m_run[r], pm[r]);
            corr[r] = __expf(m_run[r] - mn);
            m_run[r] = mn;
            ps[r] = 0.f;
        }
        #pragma unroll
        for (int n = 0; n < 4; n++) {
            #pragma unroll
            for (int r = 0; r < 4; r++) {
                float p = __expf(sc[n][r] - m_run[r]);
                ps[r] += p;
                Pl[wave][(lane >> 4) * 4 + r][n * 16 + (lane & 15)] = f2bf(p);
            }
        }
        #pragma unroll
        for (int r = 0; r < 4; r++) {
            #pragma unroll
            for (int o = 8; o >= 1; o >>= 1) ps[r] += __shfl_xor(ps[r], o);
            l_run[r] = l_run[r] * corr[r] + ps[r];
        }
        #pragma unroll
        for (int nf = 0; nf < 4; nf++) {
            f32x4 o4 = of[nf];
            o4[0] *= corr[0]; o4[1] *= corr[1]; o4[2] *= corr[2]; o4[3] *= corr[3];
            of[nf] = o4;
        }
        // O += P V
        #pragma unroll
        for (int jk = 0; jk < 2; jk++) {
            bf16x8 pf = *(const bf16x8*)&Pl[wave][lane & 15][jk * 32 + 8 * (lane >> 4)];
            #pragma unroll
            for (int nf = 0; nf < 4; nf++) {
                int d = nf * 16 + (lane & 15);
                int jb = jk * 32 + 8 * (lane >> 4);
                int a = (d << 7) + (jb << 1);
                a ^= (((d & 7) ^ ((d >> 3) & 7)) << 4);
                bf16x8 vf = *(const bf16x8*)((const char*)Vt + a);
                of[nf] = __builtin_amdgcn_mfma_f32_16x16x32_bf16(pf, vf, of[nf], 0, 0, 0);
            }
        }
    }
    float rl[4];
    #pragma unroll
    for (int r = 0; r < 4; r++) rl[r] = 1.f / l_run[r];
    const size_t orow0 = (size_t)b * NT + q0 + wave * 16 + (lane >> 4) * 4;
    #pragma unroll
    for (int nf = 0; nf < 4; nf++) {
        int col = h * NHD + nf * 16 + (lane & 15);
        #pragma unroll
        for (int r = 0; r < 4; r++)
            out[(orow0 + r) * ND + col] = f2bf(of[nf][r] * rl[r]);
    }
}

// ---------------------------------------------------------------------------
extern "C" void kernel_launch(void* const* d_in, const int* in_sizes, int n_in,
                              void* d_out, int out_size, void* d_ws, size_t ws_size,
                              hipStream_t stream) {
    const float* x     = (const float*)d_in[0];
    const float* ln1_g = (const float*)d_in[1];
    const float* ln1_b = (const float*)d_in[2];
    const float* ln2_g = (const float*)d_in[3];
    const float* ln2_b = (const float*)d_in[4];
    const float* Wq    = (const float*)d_in[5];
    const float* Wk    = (const float*)d_in[6];
    const float* Wv    = (const float*)d_in[7];
    const float* Wo    = (const float*)d_in[8];
    const float* bo    = (const float*)d_in[9];
    const float* W1    = (const float*)d_in[10];
    const float* b1    = (const float*)d_in[11];
    const float* W2    = (const float*)d_in[12];
    const float* b2    = (const float*)d_in[13];
    float* outp = (float*)d_out;

    char* w = (char*)d_ws;
    ushort_t* Wqkv_t = (ushort_t*)(w);                    // 6 MiB  (3072x1024)
    ushort_t* Wo_t   = (ushort_t*)(w + 6291456);          // 2 MiB  (1024x1024)
    ushort_t* W1_t   = (ushort_t*)(w + 8388608);          // 8 MiB  (4096x1024)
    ushort_t* W2_t   = (ushort_t*)(w + 16777216);         // 8 MiB  (1024x4096)
    ushort_t* xn     = (ushort_t*)(w + 25165824);         // 16 MiB (8192x1024), also hn
    ushort_t* qkv    = (ushort_t*)(w + 41943040);         // 48 MiB (8192x3072)
    ushort_t* attn_o = qkv + (size_t)MTOK * 3072;         // 16 MiB (8192x1024)
    ushort_t* ff1    = qkv;                               // 64 MiB (8192x4096) reuse
    float*    hbuf   = (float*)(w + 41943040 + 67108864); // 32 MiB (8192x1024 f32)
    // total ws use: 142,606,336 bytes

    dim3 tb(32, 8);
    transpose_qkv_to_bf16<<<dim3(2, 32, 48), tb, 0, stream>>>(Wq, Wk, Wv, Wqkv_t);
    transpose_to_bf16<<<dim3(32, 32), tb, 0, stream>>>(Wo, Wo_t, 1024, 1024);
    transpose_to_bf16<<<dim3(128, 32), tb, 0, stream>>>(W1, W1_t, 1024, 4096);
    transpose_to_bf16<<<dim3(32, 128), tb, 0, stream>>>(W2, W2_t, 4096, 1024);

    layernorm_to_bf16<<<MTOK, 256, 0, stream>>>(x, ln1_g, ln1_b, xn);

    gemm_bf16<false, false, false, false><<<dim3(24, 64), 256, 0, stream>>>(
        xn, Wqkv_t, nullptr, nullptr, qkv, MTOK, 3072, 1024);

    attn_kernel<<<dim3(32, 64), 256, 0, stream>>>(qkv, attn_o);

    gemm_bf16<true, false, true, true><<<dim3(8, 64), 256, 0, stream>>>(
        attn_o, Wo_t, bo, x, hbuf, MTOK, 1024, 1024);

    layernorm_to_bf16<<<MTOK, 256, 0, stream>>>(hbuf, ln2_g, ln2_b, xn);

    gemm_bf16<true, true, false, false><<<dim3(32, 64), 256, 0, stream>>>(
        xn, W1_t, b1, nullptr, ff1, MTOK, NF, 1024);

    gemm_bf16<true, false, true, true><<<dim3(8, 64), 256, 0, stream>>>(
        ff1, W2_t, b2, hbuf, outp, MTOK, 1024, NF);
}

// Round 2
// 486.865 us; speedup vs baseline: 1.2061x; 1.2061x over previous
//
#include <hip/hip_runtime.h>
#include <hip/hip_bf16.h>

#define NB 4
#define NT 2048
#define ND 1024
#define NH 16
#define NHD 64
#define NF 4096
#define MTOK (NB*NT)  // 8192

typedef float f32x4 __attribute__((ext_vector_type(4)));
typedef __bf16 bf16x8 __attribute__((ext_vector_type(8)));
typedef short s16x8 __attribute__((ext_vector_type(8)));
typedef unsigned short ushort_t;

__device__ inline ushort_t f2bf(float f) {
    unsigned int u = __builtin_bit_cast(unsigned int, f);
    unsigned int r = (u + 0x7FFFu + ((u >> 16) & 1u)) >> 16;
    return (ushort_t)r;
}

__device__ __forceinline__ void async_load16(const void* g, void* l) {
    __builtin_amdgcn_global_load_lds(
        (const __attribute__((address_space(1))) void*)g,
        (__attribute__((address_space(3))) void*)l, 16, 0, 0);
}

// ---------------------------------------------------------------------------
// Transpose-convert: src fp32 (R x C) row-major -> dst bf16 (C x R) row-major
// ---------------------------------------------------------------------------
__global__ __launch_bounds__(256)
void transpose_to_bf16(const float* __restrict__ src, ushort_t* __restrict__ dst,
                       int R, int C) {
    __shared__ float tile[32][33];
    int c0 = blockIdx.x * 32, r0 = blockIdx.y * 32;
    #pragma unroll
    for (int i = 0; i < 32; i += 8)
        tile[threadIdx.y + i][threadIdx.x] =
            src[(size_t)(r0 + threadIdx.y + i) * C + c0 + threadIdx.x];
    __syncthreads();
    #pragma unroll
    for (int i = 0; i < 32; i += 8)
        dst[(size_t)(c0 + threadIdx.y + i) * R + r0 + threadIdx.x] =
            f2bf(tile[threadIdx.x][threadIdx.y + i]);
}

// QKV weights: Wq/Wk/Wv are (H, D, HD). Build Bt (3072 x 1024) bf16 where
// row n = w*1024 + h*64 + j holds W_w[h][:, j] (K index = d).
__global__ __launch_bounds__(256)
void transpose_qkv_to_bf16(const float* __restrict__ Wq, const float* __restrict__ Wk,
                           const float* __restrict__ Wv, ushort_t* __restrict__ dst) {
    __shared__ float tile[32][33];
    int z = blockIdx.z;            // 0..47
    int w = z >> 4, h = z & 15;
    const float* src = (w == 0 ? Wq : (w == 1 ? Wk : Wv)) + (size_t)h * ND * NHD;
    ushort_t* out = dst + ((size_t)w * ND + h * NHD) * ND;
    int c0 = blockIdx.x * 32, r0 = blockIdx.y * 32;  // C=64 (j), R=1024 (d)
    #pragma unroll
    for (int i = 0; i < 32; i += 8)
        tile[threadIdx.y + i][threadIdx.x] =
            src[(size_t)(r0 + threadIdx.y + i) * NHD + c0 + threadIdx.x];
    __syncthreads();
    #pragma unroll
    for (int i = 0; i < 32; i += 8)
        out[(size_t)(c0 + threadIdx.y + i) * ND + r0 + threadIdx.x] =
            f2bf(tile[threadIdx.x][threadIdx.y + i]);
}

// ---------------------------------------------------------------------------
// LayerNorm (rows of 1024 fp32) -> bf16 out
// ---------------------------------------------------------------------------
__global__ __launch_bounds__(256)
void layernorm_to_bf16(const float* __restrict__ x, const float* __restrict__ g,
                       const float* __restrict__ bvec, ushort_t* __restrict__ out) {
    int row = blockIdx.x;
    const float4* xr = (const float4*)(x + (size_t)row * ND);
    float4 v = xr[threadIdx.x];
    float s = v.x + v.y + v.z + v.w;
    float s2 = v.x * v.x + v.y * v.y + v.z * v.z + v.w * v.w;
    #pragma unroll
    for (int o = 32; o >= 1; o >>= 1) {
        s += __shfl_xor(s, o);
        s2 += __shfl_xor(s2, o);
    }
    __shared__ float red[8];
    int wave = threadIdx.x >> 6, lane = threadIdx.x & 63;
    if (lane == 0) { red[wave] = s; red[4 + wave] = s2; }
    __syncthreads();
    float ts = red[0] + red[1] + red[2] + red[3];
    float ts2 = red[4] + red[5] + red[6] + red[7];
    float mu = ts * (1.f / ND);
    float var = ts2 * (1.f / ND) - mu * mu;
    float rs = rsqrtf(var + 1e-5f);
    float4 gv = ((const float4*)g)[threadIdx.x];
    float4 bv = ((const float4*)bvec)[threadIdx.x];
    ushort4 o4;
    o4.x = f2bf((v.x - mu) * rs * gv.x + bv.x);
    o4.y = f2bf((v.y - mu) * rs * gv.y + bv.y);
    o4.z = f2bf((v.z - mu) * rs * gv.z + bv.z);
    o4.w = f2bf((v.w - mu) * rs * gv.w + bv.w);
    ((ushort4*)(out + (size_t)row * ND))[threadIdx.x] = o4;
}

// ---------------------------------------------------------------------------
// GEMM: C[M,N] = A[M,K] (bf16) * Bt[N,K]^T (bf16)  (+bias, relu, +res) -> f32/bf16
// 128x128 tile, BK=64, 4 waves, mfma 16x16x32.
// Staging: global_load_lds width=16 into LINEAR LDS; swizzle achieved by
// pre-XORing the global source chunk (G21: linear dest + inverse-swz source).
// ---------------------------------------------------------------------------
template<bool HAS_BIAS, bool RELU, bool HAS_RES, bool OUT_F32>
__global__ __launch_bounds__(256)
void gemm_bf16(const ushort_t* __restrict__ A, const ushort_t* __restrict__ Bt,
               const float* __restrict__ bias, const float* __restrict__ res,
               void* __restrict__ outp, int M, int N, int K) {
    __shared__ __align__(16) ushort_t As[128 * 64];
    __shared__ __align__(16) ushort_t Bs[128 * 64];
    const int t = threadIdx.x;
    const int wave = t >> 6, lane = t & 63;
    const int m0 = blockIdx.y * 128, n0 = blockIdx.x * 128;
    const int wr = (wave >> 1) * 64, wc = (wave & 1) * 64;
    const int rw = lane >> 3;            // row within the wave's 8-row group
    const int ck = lane & 7;             // 16B chunk within the 128B row
    const int srcCol = (ck ^ rw) * 8;    // pre-swizzled source column (ushorts)
    f32x4 acc[4][4] = {};

    const ushort_t* Abase = A + (size_t)m0 * K + srcCol;
    const ushort_t* Bbase = Bt + (size_t)n0 * K + srcCol;

    for (int kt = 0; kt < K; kt += 64) {
        __syncthreads();   // previous compute done before overwriting LDS
        #pragma unroll
        for (int c = 0; c < 4; c++) {
            const int rowbase = c * 32 + wave * 8;          // wave-uniform
            const size_t goff = (size_t)(rowbase + rw) * K + kt;
            async_load16(Abase + goff, As + rowbase * 64);
            async_load16(Bbase + goff, Bs + rowbase * 64);
        }
        __syncthreads();   // drains vmcnt before compute
        #pragma unroll
        for (int ks = 0; ks < 2; ks++) {
            bf16x8 af[4], bfr[4];
            #pragma unroll
            for (int m = 0; m < 4; m++) {
                int row = wr + m * 16 + (lane & 15);
                int a = row * 128 + (ks * 32 + 8 * (lane >> 4)) * 2;
                a ^= ((row & 7) << 4);
                af[m] = *(const bf16x8*)((const char*)As + a);
            }
            #pragma unroll
            for (int n = 0; n < 4; n++) {
                int row = wc + n * 16 + (lane & 15);
                int a = row * 128 + (ks * 32 + 8 * (lane >> 4)) * 2;
                a ^= ((row & 7) << 4);
                bfr[n] = *(const bf16x8*)((const char*)Bs + a);
            }
            #pragma unroll
            for (int m = 0; m < 4; m++)
                #pragma unroll
                for (int n = 0; n < 4; n++)
                    acc[m][n] = __builtin_amdgcn_mfma_f32_16x16x32_bf16(
                        af[m], bfr[n], acc[m][n], 0, 0, 0);
        }
    }

    const int gr0 = m0 + wr + (lane >> 4) * 4;
    const int gc0 = n0 + wc + (lane & 15);
    #pragma unroll
    for (int mf = 0; mf < 4; mf++) {
        #pragma unroll
        for (int nf = 0; nf < 4; nf++) {
            int col = gc0 + nf * 16;
            float bb = 0.f;
            if constexpr (HAS_BIAS) bb = bias[col];
            #pragma unroll
            for (int r = 0; r < 4; r++) {
                int row = gr0 + mf * 16 + r;
                float v = acc[mf][nf][r] + bb;
                if constexpr (RELU) v = fmaxf(v, 0.f);
                if constexpr (HAS_RES) v += res[(size_t)row * N + col];
                if constexpr (OUT_F32)
                    ((float*)outp)[(size_t)row * N + col] = v;
                else
                    ((ushort_t*)outp)[(size_t)row * N + col] = f2bf(v);
            }
        }
    }
}

// ---------------------------------------------------------------------------
// Causal flash attention, load-balanced: block (pair, bh) processes q-tiles
// {pair, 31-pair} sequentially -> every block does exactly 33 kv iterations.
// Grid (16, 64) = 1024 blocks = exactly 4 resident blocks/CU. 4 waves x 16 q.
// ---------------------------------------------------------------------------
__global__ __launch_bounds__(256)
void attn_kernel(const ushort_t* __restrict__ qkv, ushort_t* __restrict__ out) {
    __shared__ __align__(16) ushort_t Ks[64][72];
    __shared__ __align__(16) ushort_t Vt[64 * 64];   // swizzled, d-major
    __shared__ __align__(16) ushort_t Pl[4][16][72];
    const int pair = blockIdx.x, bh = blockIdx.y;
    const int b = bh >> 4, h = bh & 15;
    const int t = threadIdx.x, wave = t >> 6, lane = t & 63;
    const size_t base = ((size_t)b * NT) * 3072 + h * NHD;
    const ushort_t* qb = qkv + base;
    const ushort_t* kb = qkv + base + 1024;
    const ushort_t* vb = qkv + base + 2048;
    const int srow = t >> 3, scolg = t & 7;

    for (int half = 0; half < 2; half++) {
        const int qt = half ? (31 - pair) : pair;
        const int q0 = qt * 64;

        bf16x8 qf[2];
        {
            const int qrow = q0 + wave * 16 + (lane & 15);
            const ushort_t* qp = qb + (size_t)qrow * 3072 + 8 * (lane >> 4);
            qf[0] = *(const bf16x8*)qp;
            qf[1] = *(const bf16x8*)(qp + 32);
        }
        f32x4 of[4] = {};
        float m_run[4], l_run[4];
        #pragma unroll
        for (int r = 0; r < 4; r++) { m_run[r] = -__builtin_inff(); l_run[r] = 0.f; }

        for (int kv = 0; kv <= qt; ++kv) {
            __syncthreads();
            // stage K tile (64 keys x 64 dims), row-major
            #pragma unroll
            for (int c = 0; c < 2; c++) {
                int row = srow + c * 32;
                *(bf16x8*)&Ks[row][scolg * 8] =
                    *(const bf16x8*)(kb + (size_t)(kv * 64 + row) * 3072 + scolg * 8);
            }
            // stage V tile transposed (d-major), XOR-swizzled
            {
                const ushort_t* vp = vb + (size_t)(kv * 64 + 2 * srow) * 3072 + scolg * 8;
                s16x8 v0 = *(const s16x8*)vp;
                s16x8 v1 = *(const s16x8*)(vp + 3072);
                #pragma unroll
                for (int dd = 0; dd < 8; dd++) {
                    int d = scolg * 8 + dd;
                    unsigned int wv = (unsigned int)(ushort_t)v0[dd] |
                                      ((unsigned int)(ushort_t)v1[dd] << 16);
                    int a = (d << 7) + (srow << 2);
                    a ^= (((d & 7) ^ ((d >> 3) & 7)) << 4);
                    *(unsigned int*)((char*)Vt + a) = wv;
                }
            }
            __syncthreads();

            // S = Q K^T
            f32x4 sf[4] = {};
            #pragma unroll
            for (int n = 0; n < 4; n++) {
                #pragma unroll
                for (int kd = 0; kd < 2; kd++) {
                    bf16x8 kf = *(const bf16x8*)&Ks[n * 16 + (lane & 15)][kd * 32 + 8 * (lane >> 4)];
                    sf[n] = __builtin_amdgcn_mfma_f32_16x16x32_bf16(qf[kd], kf, sf[n], 0, 0, 0);
                }
            }
            // online softmax
            float sc[4][4];
            float pm[4];
            #pragma unroll
            for (int r = 0; r < 4; r++) pm[r] = -__builtin_inff();
            const bool diag = (kv == qt);
            #pragma unroll
            for (int n = 0; n < 4; n++) {
                #pragma unroll
                for (int r = 0; r < 4; r++) {
                    float v = sf[n][r] * 0.03125f;
                    if (diag) {
                        int jg = kv * 64 + n * 16 + (lane & 15);
                        int qg = q0 + wave * 16 + (lane >> 4) * 4 + r;
                        if (jg > qg) v = -__builtin_inff();
                    }
                    sc[n][r] = v;
                    pm[r] = fmaxf(pm[r], v);
                }
            }
            #pragma unroll
            for (int r = 0; r < 4; r++) {
                #pragma unroll
                for (int o = 8; o >= 1; o >>= 1) pm[r] = fmaxf(pm[r], __shfl_xor(pm[r], o));
            }
            float corr[4], ps[4];
            #pragma unroll
            for (int r = 0; r < 4; r++) {
                float mn = fmaxf(m_run[r], pm[r]);
                corr[r] = __expf(m_run[r] - mn);
                m_run[r] = mn;
                ps[r] = 0.f;
            }
            #pragma unroll
            for (int n = 0; n < 4; n++) {
                #pragma unroll
                for (int r = 0; r < 4; r++) {
                    float p = __expf(sc[n][r] - m_run[r]);
                    ps[r] += p;
                    Pl[wave][(lane >> 4) * 4 + r][n * 16 + (lane & 15)] = f2bf(p);
                }
            }
            #pragma unroll
            for (int r = 0; r < 4; r++) {
                #pragma unroll
                for (int o = 8; o >= 1; o >>= 1) ps[r] += __shfl_xor(ps[r], o);
                l_run[r] = l_run[r] * corr[r] + ps[r];
            }
            #pragma unroll
            for (int nf = 0; nf < 4; nf++) {
                f32x4 o4 = of[nf];
                o4[0] *= corr[0]; o4[1] *= corr[1]; o4[2] *= corr[2]; o4[3] *= corr[3];
                of[nf] = o4;
            }
            // O += P V
            #pragma unroll
            for (int jk = 0; jk < 2; jk++) {
                bf16x8 pf = *(const bf16x8*)&Pl[wave][lane & 15][jk * 32 + 8 * (lane >> 4)];
                #pragma unroll
                for (int nf = 0; nf < 4; nf++) {
                    int d = nf * 16 + (lane & 15);
                    int jb = jk * 32 + 8 * (lane >> 4);
                    int a = (d << 7) + (jb << 1);
                    a ^= (((d & 7) ^ ((d >> 3) & 7)) << 4);
                    bf16x8 vf = *(const bf16x8*)((const char*)Vt + a);
                    of[nf] = __builtin_amdgcn_mfma_f32_16x16x32_bf16(pf, vf, of[nf], 0, 0, 0);
                }
            }
        }
        float rl[4];
        #pragma unroll
        for (int r = 0; r < 4; r++) rl[r] = 1.f / l_run[r];
        const size_t orow0 = (size_t)b * NT + q0 + wave * 16 + (lane >> 4) * 4;
        #pragma unroll
        for (int nf = 0; nf < 4; nf++) {
            int col = h * NHD + nf * 16 + (lane & 15);
            #pragma unroll
            for (int r = 0; r < 4; r++)
                out[(orow0 + r) * ND + col] = f2bf(of[nf][r] * rl[r]);
        }
    }
}

// ---------------------------------------------------------------------------
extern "C" void kernel_launch(void* const* d_in, const int* in_sizes, int n_in,
                              void* d_out, int out_size, void* d_ws, size_t ws_size,
                              hipStream_t stream) {
    const float* x     = (const float*)d_in[0];
    const float* ln1_g = (const float*)d_in[1];
    const float* ln1_b = (const float*)d_in[2];
    const float* ln2_g = (const float*)d_in[3];
    const float* ln2_b = (const float*)d_in[4];
    const float* Wq    = (const float*)d_in[5];
    const float* Wk    = (const float*)d_in[6];
    const float* Wv    = (const float*)d_in[7];
    const float* Wo    = (const float*)d_in[8];
    const float* bo    = (const float*)d_in[9];
    const float* W1    = (const float*)d_in[10];
    const float* b1    = (const float*)d_in[11];
    const float* W2    = (const float*)d_in[12];
    const float* b2    = (const float*)d_in[13];
    float* outp = (float*)d_out;

    char* w = (char*)d_ws;
    ushort_t* Wqkv_t = (ushort_t*)(w);                    // 6 MiB  (3072x1024)
    ushort_t* Wo_t   = (ushort_t*)(w + 6291456);          // 2 MiB  (1024x1024)
    ushort_t* W1_t   = (ushort_t*)(w + 8388608);          // 8 MiB  (4096x1024)
    ushort_t* W2_t   = (ushort_t*)(w + 16777216);         // 8 MiB  (1024x4096)
    ushort_t* xn     = (ushort_t*)(w + 25165824);         // 16 MiB (8192x1024), also hn
    ushort_t* qkv    = (ushort_t*)(w + 41943040);         // 48 MiB (8192x3072)
    ushort_t* attn_o = qkv + (size_t)MTOK * 3072;         // 16 MiB (8192x1024)
    ushort_t* ff1    = qkv;                               // 64 MiB (8192x4096) reuse
    float*    hbuf   = (float*)(w + 41943040 + 67108864); // 32 MiB (8192x1024 f32)

    dim3 tb(32, 8);
    transpose_qkv_to_bf16<<<dim3(2, 32, 48), tb, 0, stream>>>(Wq, Wk, Wv, Wqkv_t);
    transpose_to_bf16<<<dim3(32, 32), tb, 0, stream>>>(Wo, Wo_t, 1024, 1024);
    transpose_to_bf16<<<dim3(128, 32), tb, 0, stream>>>(W1, W1_t, 1024, 4096);
    transpose_to_bf16<<<dim3(32, 128), tb, 0, stream>>>(W2, W2_t, 4096, 1024);

    layernorm_to_bf16<<<MTOK, 256, 0, stream>>>(x, ln1_g, ln1_b, xn);

    gemm_bf16<false, false, false, false><<<dim3(24, 64), 256, 0, stream>>>(
        xn, Wqkv_t, nullptr, nullptr, qkv, MTOK, 3072, 1024);

    attn_kernel<<<dim3(16, 64), 256, 0, stream>>>(qkv, attn_o);

    gemm_bf16<true, false, true, true><<<dim3(8, 64), 256, 0, stream>>>(
        attn_o, Wo_t, bo, x, hbuf, MTOK, 1024, 1024);

    layernorm_to_bf16<<<MTOK, 256, 0, stream>>>(hbuf, ln2_g, ln2_b, xn);

    gemm_bf16<true, true, false, false><<<dim3(32, 64), 256, 0, stream>>>(
        xn, W1_t, b1, nullptr, ff1, MTOK, NF, 1024);

    gemm_bf16<true, false, true, true><<<dim3(8, 64), 256, 0, stream>>>(
        ff1, W2_t, b2, hbuf, outp, MTOK, 1024, NF);
}

// Round 4
// 407.979 us; speedup vs baseline: 1.4393x; 1.1934x over previous
//
#include <hip/hip_runtime.h>
#include <hip/hip_bf16.h>

#define NB 4
#define NT 2048
#define ND 1024
#define NH 16
#define NHD 64
#define NF 4096
#define MTOK (NB*NT)  // 8192

typedef float f32x4 __attribute__((ext_vector_type(4)));
typedef __bf16 bf16x8 __attribute__((ext_vector_type(8)));
typedef short s16x8 __attribute__((ext_vector_type(8)));
typedef short s16x4v __attribute__((ext_vector_type(4)));
typedef unsigned short ushort_t;

__device__ inline ushort_t f2bf(float f) {
    unsigned int u = __builtin_bit_cast(unsigned int, f);
    unsigned int r = (u + 0x7FFFu + ((u >> 16) & 1u)) >> 16;
    return (ushort_t)r;
}

__device__ __forceinline__ void async_load16(const void* g, void* l) {
    __builtin_amdgcn_global_load_lds(
        (const __attribute__((address_space(1))) void*)g,
        (__attribute__((address_space(3))) void*)l, 16, 0, 0);
}

__device__ __forceinline__ unsigned int cvt_pk_bf16(float lo, float hi) {
    unsigned int r;
    asm("v_cvt_pk_bf16_f32 %0, %1, %2" : "=v"(r) : "v"(lo), "v"(hi));
    return r;
}

// ---------------------------------------------------------------------------
// Transpose-convert: src fp32 (R x C) row-major -> dst bf16 (C x R) row-major
// ---------------------------------------------------------------------------
__global__ __launch_bounds__(256)
void transpose_to_bf16(const float* __restrict__ src, ushort_t* __restrict__ dst,
                       int R, int C) {
    __shared__ float tile[32][33];
    int c0 = blockIdx.x * 32, r0 = blockIdx.y * 32;
    #pragma unroll
    for (int i = 0; i < 32; i += 8)
        tile[threadIdx.y + i][threadIdx.x] =
            src[(size_t)(r0 + threadIdx.y + i) * C + c0 + threadIdx.x];
    __syncthreads();
    #pragma unroll
    for (int i = 0; i < 32; i += 8)
        dst[(size_t)(c0 + threadIdx.y + i) * R + r0 + threadIdx.x] =
            f2bf(tile[threadIdx.x][threadIdx.y + i]);
}

// QKV weights: Wq/Wk/Wv are (H, D, HD). Build Bt (3072 x 1024) bf16 where
// row n = w*1024 + h*64 + j holds W_w[h][:, j]. Wq is pre-scaled by 1/32
// (exact exponent shift) so attention scores come out of QK^T pre-scaled.
__global__ __launch_bounds__(256)
void transpose_qkv_to_bf16(const float* __restrict__ Wq, const float* __restrict__ Wk,
                           const float* __restrict__ Wv, ushort_t* __restrict__ dst) {
    __shared__ float tile[32][33];
    int z = blockIdx.z;            // 0..47
    int w = z >> 4, h = z & 15;
    const float* src = (w == 0 ? Wq : (w == 1 ? Wk : Wv)) + (size_t)h * ND * NHD;
    const float sc = (w == 0) ? 0.03125f : 1.0f;
    ushort_t* out = dst + ((size_t)w * ND + h * NHD) * ND;
    int c0 = blockIdx.x * 32, r0 = blockIdx.y * 32;
    #pragma unroll
    for (int i = 0; i < 32; i += 8)
        tile[threadIdx.y + i][threadIdx.x] =
            src[(size_t)(r0 + threadIdx.y + i) * NHD + c0 + threadIdx.x];
    __syncthreads();
    #pragma unroll
    for (int i = 0; i < 32; i += 8)
        out[(size_t)(c0 + threadIdx.y + i) * ND + r0 + threadIdx.x] =
            f2bf(tile[threadIdx.x][threadIdx.y + i] * sc);
}

// ---------------------------------------------------------------------------
// LayerNorm (rows of 1024 fp32) -> bf16 out
// ---------------------------------------------------------------------------
__global__ __launch_bounds__(256)
void layernorm_to_bf16(const float* __restrict__ x, const float* __restrict__ g,
                       const float* __restrict__ bvec, ushort_t* __restrict__ out) {
    int row = blockIdx.x;
    const float4* xr = (const float4*)(x + (size_t)row * ND);
    float4 v = xr[threadIdx.x];
    float s = v.x + v.y + v.z + v.w;
    float s2 = v.x * v.x + v.y * v.y + v.z * v.z + v.w * v.w;
    #pragma unroll
    for (int o = 32; o >= 1; o >>= 1) {
        s += __shfl_xor(s, o);
        s2 += __shfl_xor(s2, o);
    }
    __shared__ float red[8];
    int wave = threadIdx.x >> 6, lane = threadIdx.x & 63;
    if (lane == 0) { red[wave] = s; red[4 + wave] = s2; }
    __syncthreads();
    float ts = red[0] + red[1] + red[2] + red[3];
    float ts2 = red[4] + red[5] + red[6] + red[7];
    float mu = ts * (1.f / ND);
    float var = ts2 * (1.f / ND) - mu * mu;
    float rs = rsqrtf(var + 1e-5f);
    float4 gv = ((const float4*)g)[threadIdx.x];
    float4 bv = ((const float4*)bvec)[threadIdx.x];
    ushort4 o4;
    o4.x = f2bf((v.x - mu) * rs * gv.x + bv.x);
    o4.y = f2bf((v.y - mu) * rs * gv.y + bv.y);
    o4.z = f2bf((v.z - mu) * rs * gv.z + bv.z);
    o4.w = f2bf((v.w - mu) * rs * gv.w + bv.w);
    ((ushort4*)(out + (size_t)row * ND))[threadIdx.x] = o4;
}

// ---------------------------------------------------------------------------
// GEMM: C[M,N] = A[M,K] (bf16) * Bt[N,K]^T (bf16)  (+bias, relu, +res)
// 128x128 tile, BK=64, 4 waves, mfma 16x16x32, global_load_lds staging.
// ---------------------------------------------------------------------------
template<bool HAS_BIAS, bool RELU, bool HAS_RES, bool OUT_F32>
__global__ __launch_bounds__(256)
void gemm_bf16(const ushort_t* __restrict__ A, const ushort_t* __restrict__ Bt,
               const float* __restrict__ bias, const float* __restrict__ res,
               void* __restrict__ outp, int M, int N, int K) {
    __shared__ __align__(16) ushort_t As[128 * 64];
    __shared__ __align__(16) ushort_t Bs[128 * 64];
    const int t = threadIdx.x;
    const int wave = t >> 6, lane = t & 63;
    const int m0 = blockIdx.y * 128, n0 = blockIdx.x * 128;
    const int wr = (wave >> 1) * 64, wc = (wave & 1) * 64;
    const int rw = lane >> 3;            // row within the wave's 8-row group
    const int ck = lane & 7;             // 16B chunk within the 128B row
    const int srcCol = (ck ^ rw) * 8;    // pre-swizzled source column (ushorts)
    f32x4 acc[4][4] = {};

    const ushort_t* Abase = A + (size_t)m0 * K + srcCol;
    const ushort_t* Bbase = Bt + (size_t)n0 * K + srcCol;

    for (int kt = 0; kt < K; kt += 64) {
        __syncthreads();
        #pragma unroll
        for (int c = 0; c < 4; c++) {
            const int rowbase = c * 32 + wave * 8;          // wave-uniform
            const size_t goff = (size_t)(rowbase + rw) * K + kt;
            async_load16(Abase + goff, As + rowbase * 64);
            async_load16(Bbase + goff, Bs + rowbase * 64);
        }
        __syncthreads();
        #pragma unroll
        for (int ks = 0; ks < 2; ks++) {
            bf16x8 af[4], bfr[4];
            #pragma unroll
            for (int m = 0; m < 4; m++) {
                int row = wr + m * 16 + (lane & 15);
                int a = row * 128 + (ks * 32 + 8 * (lane >> 4)) * 2;
                a ^= ((row & 7) << 4);
                af[m] = *(const bf16x8*)((const char*)As + a);
            }
            #pragma unroll
            for (int n = 0; n < 4; n++) {
                int row = wc + n * 16 + (lane & 15);
                int a = row * 128 + (ks * 32 + 8 * (lane >> 4)) * 2;
                a ^= ((row & 7) << 4);
                bfr[n] = *(const bf16x8*)((const char*)Bs + a);
            }
            #pragma unroll
            for (int m = 0; m < 4; m++)
                #pragma unroll
                for (int n = 0; n < 4; n++)
                    acc[m][n] = __builtin_amdgcn_mfma_f32_16x16x32_bf16(
                        af[m], bfr[n], acc[m][n], 0, 0, 0);
        }
    }

    const int gr0 = m0 + wr + (lane >> 4) * 4;
    const int gc0 = n0 + wc + (lane & 15);
    #pragma unroll
    for (int mf = 0; mf < 4; mf++) {
        #pragma unroll
        for (int nf = 0; nf < 4; nf++) {
            int col = gc0 + nf * 16;
            float bb = 0.f;
            if constexpr (HAS_BIAS) bb = bias[col];
            #pragma unroll
            for (int r = 0; r < 4; r++) {
                int row = gr0 + mf * 16 + r;
                float v = acc[mf][nf][r] + bb;
                if constexpr (RELU) v = fmaxf(v, 0.f);
                if constexpr (HAS_RES) v += res[(size_t)row * N + col];
                if constexpr (OUT_F32)
                    ((float*)outp)[(size_t)row * N + col] = v;
                else
                    ((ushort_t*)outp)[(size_t)row * N + col] = f2bf(v);
            }
        }
    }
}

// ---------------------------------------------------------------------------
// Causal flash attention, QBLK=128 (8 waves x 16 q-rows), KVBLK=64.
// Swapped QK^T: sf = mfma(K, Q) -> lane holds S^T[k = n*16+4g+r][q = lane&15].
// (Both operands use the identical, round-2-verified 16x16x32 fragment
// pattern, so swapping is layout-safe.) Softmax fully in-register.
// PV: P packed to u32 k-pair words, bounced through a per-wave LDS buffer
// (no barrier: intra-wave), read back as the verified 16x16x32 B-fragment;
// O^T += V^T P^T with the round-2-verified Vt addressing.
// Pairs (qt, 15-qt): every block does exactly 34 kv iterations.
// ---------------------------------------------------------------------------
__global__ __launch_bounds__(512)
void attn_kernel(const ushort_t* __restrict__ qkv, ushort_t* __restrict__ out) {
    __shared__ __align__(16) ushort_t Ks[64][72];
    __shared__ __align__(16) ushort_t Vt[64 * 64];   // d-major, XOR-swizzled
    __shared__ unsigned int Pw[8][16][35];           // per-wave P words
    const int pairIdx = blockIdx.x, bh = blockIdx.y;
    const int b = bh >> 4, h = bh & 15;
    const int t = threadIdx.x, wave = t >> 6, lane = t & 63;
    const int g = lane >> 4, q16 = lane & 15;
    const size_t base = ((size_t)b * NT) * 3072 + h * NHD;
    const ushort_t* qb = qkv + base;
    const ushort_t* kb = qkv + base + 1024;
    const ushort_t* vb = qkv + base + 2048;
    const int krow = t >> 3, kcol = (t & 7) * 8;     // K staging: 64x64
    const int vkp = t >> 4, vdg = t & 15;            // V staging: k-pair, 4-d group
    unsigned int* pr = &Pw[wave][q16][0];

    for (int half = 0; half < 2; half++) {
        const int qt = half ? (15 - pairIdx) : pairIdx;
        const int q0 = qt * 128;
        const int wq0 = q0 + wave * 16;
        const int wq = wq0 + q16;
        bf16x8 qf[2];
        {
            const ushort_t* qp = qb + (size_t)wq * 3072 + 8 * g;
            qf[0] = *(const bf16x8*)qp;
            qf[1] = *(const bf16x8*)(qp + 32);
        }
        f32x4 of[4] = {};
        float m_run = -1.0e30f, l_run = 0.f;
        const int nkv = 2 * qt + 2;

        for (int kv = 0; kv < nkv; ++kv) {
            __syncthreads();
            // stage K tile (64 keys x 64 dims) row-major
            *(bf16x8*)&Ks[krow][kcol] =
                *(const bf16x8*)(kb + (size_t)(kv * 64 + krow) * 3072 + kcol);
            // stage V tile transposed (d-major), XOR-swizzled
            {
                const ushort_t* vp = vb + (size_t)(kv * 64 + 2 * vkp) * 3072 + vdg * 4;
                s16x4v v0 = *(const s16x4v*)vp;
                s16x4v v1 = *(const s16x4v*)(vp + 3072);
                #pragma unroll
                for (int dd = 0; dd < 4; dd++) {
                    int d = vdg * 4 + dd;
                    unsigned int wv = (unsigned int)(ushort_t)v0[dd] |
                                      ((unsigned int)(ushort_t)v1[dd] << 16);
                    int a = (d << 7) + (vkp << 2);
                    a ^= (((d & 7) ^ ((d >> 3) & 7)) << 4);
                    *(unsigned int*)((char*)Vt + a) = wv;
                }
            }
            __syncthreads();

            const int kbase = kv * 64;
            if (kbase > wq0 + 15) continue;   // wave fully beyond causal reach

            // S^T = K Q^T  (swapped operands)
            f32x4 sf[4] = {};
            #pragma unroll
            for (int n = 0; n < 4; n++) {
                #pragma unroll
                for (int kd = 0; kd < 2; kd++) {
                    bf16x8 kf = *(const bf16x8*)&Ks[n * 16 + q16][kd * 32 + 8 * g];
                    sf[n] = __builtin_amdgcn_mfma_f32_16x16x32_bf16(kf, qf[kd], sf[n], 0, 0, 0);
                }
            }

            const bool partial = (kbase + 63 > wq0);
            float p[4][4];
            #pragma unroll
            for (int n = 0; n < 4; n++)
                #pragma unroll
                for (int r = 0; r < 4; r++) {
                    float v = sf[n][r];
                    if (partial) {
                        int kg = kbase + n * 16 + 4 * g + r;
                        if (kg > wq) v = -1.0e30f;
                    }
                    p[n][r] = v;
                }

            // row max: 15 in-lane + 2 shuffles (lanes l, l^16, l^32, l^48 share q)
            float mx0 = fmaxf(fmaxf(p[0][0], p[0][1]), fmaxf(p[0][2], p[0][3]));
            float mx1 = fmaxf(fmaxf(p[1][0], p[1][1]), fmaxf(p[1][2], p[1][3]));
            float mx2 = fmaxf(fmaxf(p[2][0], p[2][1]), fmaxf(p[2][2], p[2][3]));
            float mx3 = fmaxf(fmaxf(p[3][0], p[3][1]), fmaxf(p[3][2], p[3][3]));
            float mx = fmaxf(fmaxf(mx0, mx1), fmaxf(mx2, mx3));
            mx = fmaxf(mx, __shfl_xor(mx, 16));
            mx = fmaxf(mx, __shfl_xor(mx, 32));

            // defer-max (THR=8): only rescale when the max actually moves
            if (__any(mx > m_run + 8.f)) {
                float mn = fmaxf(m_run, mx);
                float corr = __expf(m_run - mn);
                m_run = mn;
                l_run *= corr;
                #pragma unroll
                for (int nf = 0; nf < 4; nf++) {
                    f32x4 o4 = of[nf];
                    o4[0] *= corr; o4[1] *= corr; o4[2] *= corr; o4[3] *= corr;
                    of[nf] = o4;
                }
            }

            float ps = 0.f;
            #pragma unroll
            for (int n = 0; n < 4; n++)
                #pragma unroll
                for (int r = 0; r < 4; r++) {
                    p[n][r] = __expf(p[n][r] - m_run);
                    ps += p[n][r];
                }
            ps += __shfl_xor(ps, 16);
            ps += __shfl_xor(ps, 32);
            l_run += ps;

            // pack P into u32 k-pair words; word w covers k = 2w, 2w+1
            #pragma unroll
            for (int n = 0; n < 4; n++) {
                pr[8 * n + 2 * g + 0] = cvt_pk_bf16(p[n][0], p[n][1]);
                pr[8 * n + 2 * g + 1] = cvt_pk_bf16(p[n][2], p[n][3]);
            }
            // O^T += V^T P^T via 8 x mfma_16x16x32 (all-verified fragments)
            #pragma unroll
            for (int kbk = 0; kbk < 2; kbk++) {
                uint4 pu;
                pu.x = pr[16 * kbk + 4 * g + 0];
                pu.y = pr[16 * kbk + 4 * g + 1];
                pu.z = pr[16 * kbk + 4 * g + 2];
                pu.w = pr[16 * kbk + 4 * g + 3];
                bf16x8 pf = __builtin_bit_cast(bf16x8, pu);
                #pragma unroll
                for (int nf = 0; nf < 4; nf++) {
                    const int d = nf * 16 + q16;
                    int a = (d << 7) + (kbk * 64 + 16 * g);
                    a ^= (((d & 7) ^ ((d >> 3) & 7)) << 4);
                    bf16x8 vf = *(const bf16x8*)((const char*)Vt + a);
                    of[nf] = __builtin_amdgcn_mfma_f32_16x16x32_bf16(
                        vf, pf, of[nf], 0, 0, 0);
                }
            }
        }

        // epilogue: of[nf][r] = O[q = wq][d = nf*16 + 4g + r]
        float rl = 1.f / l_run;
        const size_t orow = (size_t)b * NT + q0 + wave * 16 + q16;
        #pragma unroll
        for (int nf = 0; nf < 4; nf++) {
            ushort4 o4;
            o4.x = f2bf(of[nf][0] * rl);
            o4.y = f2bf(of[nf][1] * rl);
            o4.z = f2bf(of[nf][2] * rl);
            o4.w = f2bf(of[nf][3] * rl);
            *(ushort4*)(out + orow * ND + h * NHD + nf * 16 + 4 * g) = o4;
        }
    }
}

// ---------------------------------------------------------------------------
extern "C" void kernel_launch(void* const* d_in, const int* in_sizes, int n_in,
                              void* d_out, int out_size, void* d_ws, size_t ws_size,
                              hipStream_t stream) {
    const float* x     = (const float*)d_in[0];
    const float* ln1_g = (const float*)d_in[1];
    const float* ln1_b = (const float*)d_in[2];
    const float* ln2_g = (const float*)d_in[3];
    const float* ln2_b = (const float*)d_in[4];
    const float* Wq    = (const float*)d_in[5];
    const float* Wk    = (const float*)d_in[6];
    const float* Wv    = (const float*)d_in[7];
    const float* Wo    = (const float*)d_in[8];
    const float* bo    = (const float*)d_in[9];
    const float* W1    = (const float*)d_in[10];
    const float* b1    = (const float*)d_in[11];
    const float* W2    = (const float*)d_in[12];
    const float* b2    = (const float*)d_in[13];
    float* outp = (float*)d_out;

    char* w = (char*)d_ws;
    ushort_t* Wqkv_t = (ushort_t*)(w);                    // 6 MiB  (3072x1024)
    ushort_t* Wo_t   = (ushort_t*)(w + 6291456);          // 2 MiB  (1024x1024)
    ushort_t* W1_t   = (ushort_t*)(w + 8388608);          // 8 MiB  (4096x1024)
    ushort_t* W2_t   = (ushort_t*)(w + 16777216);         // 8 MiB  (1024x4096)
    ushort_t* xn     = (ushort_t*)(w + 25165824);         // 16 MiB (8192x1024), also hn
    ushort_t* qkv    = (ushort_t*)(w + 41943040);         // 48 MiB (8192x3072)
    ushort_t* attn_o = qkv + (size_t)MTOK * 3072;         // 16 MiB (8192x1024)
    ushort_t* ff1    = qkv;                               // 64 MiB (8192x4096) reuse
    float*    hbuf   = (float*)(w + 41943040 + 67108864); // 32 MiB (8192x1024 f32)

    dim3 tb(32, 8);
    transpose_qkv_to_bf16<<<dim3(2, 32, 48), tb, 0, stream>>>(Wq, Wk, Wv, Wqkv_t);
    transpose_to_bf16<<<dim3(32, 32), tb, 0, stream>>>(Wo, Wo_t, 1024, 1024);
    transpose_to_bf16<<<dim3(128, 32), tb, 0, stream>>>(W1, W1_t, 1024, 4096);
    transpose_to_bf16<<<dim3(32, 128), tb, 0, stream>>>(W2, W2_t, 4096, 1024);

    layernorm_to_bf16<<<MTOK, 256, 0, stream>>>(x, ln1_g, ln1_b, xn);

    gemm_bf16<false, false, false, false><<<dim3(24, 64), 256, 0, stream>>>(
        xn, Wqkv_t, nullptr, nullptr, qkv, MTOK, 3072, 1024);

    attn_kernel<<<dim3(8, 64), 512, 0, stream>>>(qkv, attn_o);

    gemm_bf16<true, false, true, true><<<dim3(8, 64), 256, 0, stream>>>(
        attn_o, Wo_t, bo, x, hbuf, MTOK, 1024, 1024);

    layernorm_to_bf16<<<MTOK, 256, 0, stream>>>(hbuf, ln2_g, ln2_b, xn);

    gemm_bf16<true, true, false, false><<<dim3(32, 64), 256, 0, stream>>>(
        xn, W1_t, b1, nullptr, ff1, MTOK, NF, 1024);

    gemm_bf16<true, false, true, true><<<dim3(8, 64), 256, 0, stream>>>(
        ff1, W2_t, b2, hbuf, outp, MTOK, 1024, NF);
}

// Round 5
// 400.405 us; speedup vs baseline: 1.4665x; 1.0189x over previous
//
#include <hip/hip_runtime.h>
#include <hip/hip_bf16.h>

#define NB 4
#define NT 2048
#define ND 1024
#define NH 16
#define NHD 64
#define NF 4096
#define MTOK (NB*NT)  // 8192

typedef float f32x4 __attribute__((ext_vector_type(4)));
typedef __bf16 bf16x8 __attribute__((ext_vector_type(8)));
typedef short s16x8 __attribute__((ext_vector_type(8)));
typedef short s16x4v __attribute__((ext_vector_type(4)));
typedef unsigned short ushort_t;

__device__ inline ushort_t f2bf(float f) {
    unsigned int u = __builtin_bit_cast(unsigned int, f);
    unsigned int r = (u + 0x7FFFu + ((u >> 16) & 1u)) >> 16;
    return (ushort_t)r;
}

__device__ __forceinline__ void async_load16(const void* g, void* l) {
    __builtin_amdgcn_global_load_lds(
        (const __attribute__((address_space(1))) void*)g,
        (__attribute__((address_space(3))) void*)l, 16, 0, 0);
}

__device__ __forceinline__ unsigned int cvt_pk_bf16(float lo, float hi) {
    unsigned int r;
    asm("v_cvt_pk_bf16_f32 %0, %1, %2" : "=v"(r) : "v"(lo), "v"(hi));
    return r;
}

__device__ __forceinline__ float exp2_fast(float x) {
    float r;
    asm("v_exp_f32 %0, %1" : "=v"(r) : "v"(x));
    return r;
}

// ---------------------------------------------------------------------------
// Transpose-convert: src fp32 (R x C) row-major -> dst bf16 (C x R) row-major
// ---------------------------------------------------------------------------
__global__ __launch_bounds__(256)
void transpose_to_bf16(const float* __restrict__ src, ushort_t* __restrict__ dst,
                       int R, int C) {
    __shared__ float tile[32][33];
    int c0 = blockIdx.x * 32, r0 = blockIdx.y * 32;
    #pragma unroll
    for (int i = 0; i < 32; i += 8)
        tile[threadIdx.y + i][threadIdx.x] =
            src[(size_t)(r0 + threadIdx.y + i) * C + c0 + threadIdx.x];
    __syncthreads();
    #pragma unroll
    for (int i = 0; i < 32; i += 8)
        dst[(size_t)(c0 + threadIdx.y + i) * R + r0 + threadIdx.x] =
            f2bf(tile[threadIdx.x][threadIdx.y + i]);
}

// QKV weights: Wq/Wk/Wv are (H, D, HD). Build Bt (3072 x 1024) bf16.
// Wq pre-scaled by (1/32)*log2(e): QK^T scores come out in exp2 domain.
__global__ __launch_bounds__(256)
void transpose_qkv_to_bf16(const float* __restrict__ Wq, const float* __restrict__ Wk,
                           const float* __restrict__ Wv, ushort_t* __restrict__ dst) {
    __shared__ float tile[32][33];
    int z = blockIdx.z;            // 0..47
    int w = z >> 4, h = z & 15;
    const float* src = (w == 0 ? Wq : (w == 1 ? Wk : Wv)) + (size_t)h * ND * NHD;
    const float sc = (w == 0) ? 0.03125f * 1.44269504f : 1.0f;
    ushort_t* out = dst + ((size_t)w * ND + h * NHD) * ND;
    int c0 = blockIdx.x * 32, r0 = blockIdx.y * 32;
    #pragma unroll
    for (int i = 0; i < 32; i += 8)
        tile[threadIdx.y + i][threadIdx.x] =
            src[(size_t)(r0 + threadIdx.y + i) * NHD + c0 + threadIdx.x];
    __syncthreads();
    #pragma unroll
    for (int i = 0; i < 32; i += 8)
        out[(size_t)(c0 + threadIdx.y + i) * ND + r0 + threadIdx.x] =
            f2bf(tile[threadIdx.x][threadIdx.y + i] * sc);
}

// ---------------------------------------------------------------------------
// LayerNorm (rows of 1024 fp32) -> bf16 out
// ---------------------------------------------------------------------------
__global__ __launch_bounds__(256)
void layernorm_to_bf16(const float* __restrict__ x, const float* __restrict__ g,
                       const float* __restrict__ bvec, ushort_t* __restrict__ out) {
    int row = blockIdx.x;
    const float4* xr = (const float4*)(x + (size_t)row * ND);
    float4 v = xr[threadIdx.x];
    float s = v.x + v.y + v.z + v.w;
    float s2 = v.x * v.x + v.y * v.y + v.z * v.z + v.w * v.w;
    #pragma unroll
    for (int o = 32; o >= 1; o >>= 1) {
        s += __shfl_xor(s, o);
        s2 += __shfl_xor(s2, o);
    }
    __shared__ float red[8];
    int wave = threadIdx.x >> 6, lane = threadIdx.x & 63;
    if (lane == 0) { red[wave] = s; red[4 + wave] = s2; }
    __syncthreads();
    float ts = red[0] + red[1] + red[2] + red[3];
    float ts2 = red[4] + red[5] + red[6] + red[7];
    float mu = ts * (1.f / ND);
    float var = ts2 * (1.f / ND) - mu * mu;
    float rs = rsqrtf(var + 1e-5f);
    float4 gv = ((const float4*)g)[threadIdx.x];
    float4 bv = ((const float4*)bvec)[threadIdx.x];
    ushort4 o4;
    o4.x = f2bf((v.x - mu) * rs * gv.x + bv.x);
    o4.y = f2bf((v.y - mu) * rs * gv.y + bv.y);
    o4.z = f2bf((v.z - mu) * rs * gv.z + bv.z);
    o4.w = f2bf((v.w - mu) * rs * gv.w + bv.w);
    ((ushort4*)(out + (size_t)row * ND))[threadIdx.x] = o4;
}

// ---------------------------------------------------------------------------
// GEMM: C[M,N] = A[M,K] (bf16) * Bt[N,K]^T (bf16)  (+bias, relu, +res)
// 128x128 tile, BK=64, 4 waves, mfma 16x16x32, global_load_lds staging,
// bijective XCD-aware block swizzle (nwg % 8 == 0 for all launches).
// ---------------------------------------------------------------------------
template<bool HAS_BIAS, bool RELU, bool HAS_RES, bool OUT_F32>
__global__ __launch_bounds__(256)
void gemm_bf16(const ushort_t* __restrict__ A, const ushort_t* __restrict__ Bt,
               const float* __restrict__ bias, const float* __restrict__ res,
               void* __restrict__ outp, int M, int N, int K) {
    __shared__ __align__(16) ushort_t As[128 * 64];
    __shared__ __align__(16) ushort_t Bs[128 * 64];
    const int t = threadIdx.x;
    const int wave = t >> 6, lane = t & 63;
    int wid = blockIdx.y * gridDim.x + blockIdx.x;
    const int cpx = (gridDim.x * gridDim.y) >> 3;
    wid = (wid & 7) * cpx + (wid >> 3);
    const int m0 = (wid / gridDim.x) * 128, n0 = (wid % gridDim.x) * 128;
    const int wr = (wave >> 1) * 64, wc = (wave & 1) * 64;
    const int rw = lane >> 3;            // row within the wave's 8-row group
    const int ck = lane & 7;             // 16B chunk within the 128B row
    const int srcCol = (ck ^ rw) * 8;    // pre-swizzled source column (ushorts)
    f32x4 acc[4][4] = {};

    const ushort_t* Abase = A + (size_t)m0 * K + srcCol;
    const ushort_t* Bbase = Bt + (size_t)n0 * K + srcCol;

    for (int kt = 0; kt < K; kt += 64) {
        __syncthreads();
        #pragma unroll
        for (int c = 0; c < 4; c++) {
            const int rowbase = c * 32 + wave * 8;          // wave-uniform
            const size_t goff = (size_t)(rowbase + rw) * K + kt;
            async_load16(Abase + goff, As + rowbase * 64);
            async_load16(Bbase + goff, Bs + rowbase * 64);
        }
        __syncthreads();
        #pragma unroll
        for (int ks = 0; ks < 2; ks++) {
            bf16x8 af[4], bfr[4];
            #pragma unroll
            for (int m = 0; m < 4; m++) {
                int row = wr + m * 16 + (lane & 15);
                int a = row * 128 + (ks * 32 + 8 * (lane >> 4)) * 2;
                a ^= ((row & 7) << 4);
                af[m] = *(const bf16x8*)((const char*)As + a);
            }
            #pragma unroll
            for (int n = 0; n < 4; n++) {
                int row = wc + n * 16 + (lane & 15);
                int a = row * 128 + (ks * 32 + 8 * (lane >> 4)) * 2;
                a ^= ((row & 7) << 4);
                bfr[n] = *(const bf16x8*)((const char*)Bs + a);
            }
            #pragma unroll
            for (int m = 0; m < 4; m++)
                #pragma unroll
                for (int n = 0; n < 4; n++)
                    acc[m][n] = __builtin_amdgcn_mfma_f32_16x16x32_bf16(
                        af[m], bfr[n], acc[m][n], 0, 0, 0);
        }
    }

    const int gr0 = m0 + wr + (lane >> 4) * 4;
    const int gc0 = n0 + wc + (lane & 15);
    #pragma unroll
    for (int mf = 0; mf < 4; mf++) {
        #pragma unroll
        for (int nf = 0; nf < 4; nf++) {
            int col = gc0 + nf * 16;
            float bb = 0.f;
            if constexpr (HAS_BIAS) bb = bias[col];
            #pragma unroll
            for (int r = 0; r < 4; r++) {
                int row = gr0 + mf * 16 + r;
                float v = acc[mf][nf][r] + bb;
                if constexpr (RELU) v = fmaxf(v, 0.f);
                if constexpr (HAS_RES) v += res[(size_t)row * N + col];
                if constexpr (OUT_F32)
                    ((float*)outp)[(size_t)row * N + col] = v;
                else
                    ((ushort_t*)outp)[(size_t)row * N + col] = f2bf(v);
            }
        }
    }
}

// ---------------------------------------------------------------------------
// Causal flash attention. QBLK=256: 8 waves x 32 q-rows (2 q-col-blocks per
// wave), KVBLK=64. K/V fragments loaded once per wave, used by BOTH q-blocks
// (halves LDS read traffic per unit work). K staged via global_load_lds with
// pre-swizzled source (verified GEMM pattern). Softmax in exp2 domain
// (log2e folded into Wq). Pairs (qt, 7-qt): every block exactly 36 kv iters.
// Grid (4,64) = 256 blocks; XCD swizzle co-locates each bh's 4 blocks.
// ---------------------------------------------------------------------------
__global__ __launch_bounds__(512)
void attn_kernel(const ushort_t* __restrict__ qkv, ushort_t* __restrict__ out) {
    __shared__ __align__(16) ushort_t Ks[64 * 64];   // linear, XOR-swizzle on read
    __shared__ __align__(16) ushort_t Vt[64 * 64];   // d-major, XOR-swizzled
    __shared__ unsigned int Pw[8][32][35];           // per-wave P words
    const int L = blockIdx.y * gridDim.x + blockIdx.x;   // dispatch-linear id
    const int xcd = L & 7, kk = L >> 3;
    const int bh = ((kk & 7) << 3) | xcd;     // 4 pair-blocks of a bh -> one XCD
    const int pairIdx = kk >> 3;              // 0..3
    const int b = bh >> 4, h = bh & 15;
    const int t = threadIdx.x, wave = t >> 6, lane = t & 63;
    const int g = lane >> 4, q16 = lane & 15;
    const size_t base = ((size_t)b * NT) * 3072 + h * NHD;
    const ushort_t* qp_base = qkv + base;
    const ushort_t* kb = qkv + base + 1024;
    const ushort_t* vb = qkv + base + 2048;
    // K staging: wave stages rows [wave*8, wave*8+8); HW adds lane*16 to dest
    const int krw = lane >> 3, kck = lane & 7;
    ushort_t* klds = Ks + wave * 8 * 64;
    const int ksrc = (kck ^ krw) * 8;         // pre-swizzled source column
    // V staging
    const int vkp = t >> 4, vdg = t & 15;

    for (int half = 0; half < 2; half++) {
        const int qt = half ? (7 - pairIdx) : pairIdx;
        const int q0 = qt * 256;
        const int wq0 = q0 + wave * 32;
        bf16x8 qf[2][2];
        #pragma unroll
        for (int qb2 = 0; qb2 < 2; qb2++) {
            const ushort_t* qp = qp_base + (size_t)(wq0 + 16 * qb2 + q16) * 3072 + 8 * g;
            qf[qb2][0] = *(const bf16x8*)qp;
            qf[qb2][1] = *(const bf16x8*)(qp + 32);
        }
        f32x4 of[2][4] = {};
        float m_run[2] = {-1.0e30f, -1.0e30f};
        float l_run[2] = {0.f, 0.f};
        const int nkv = 4 * qt + 4;

        for (int kv = 0; kv < nkv; ++kv) {
            __syncthreads();
            // K: one global_load_lds per thread (8KB tile)
            async_load16(kb + (size_t)(kv * 64 + wave * 8 + krw) * 3072 + ksrc, klds);
            // V: register transpose to d-major, XOR-swizzled
            {
                const ushort_t* vp = vb + (size_t)(kv * 64 + 2 * vkp) * 3072 + vdg * 4;
                s16x4v v0 = *(const s16x4v*)vp;
                s16x4v v1 = *(const s16x4v*)(vp + 3072);
                #pragma unroll
                for (int dd = 0; dd < 4; dd++) {
                    int d = vdg * 4 + dd;
                    unsigned int wv = (unsigned int)(ushort_t)v0[dd] |
                                      ((unsigned int)(ushort_t)v1[dd] << 16);
                    int a = (d << 7) + (vkp << 2);
                    a ^= (((d & 7) ^ ((d >> 3) & 7)) << 4);
                    *(unsigned int*)((char*)Vt + a) = wv;
                }
            }
            __syncthreads();

            const int kbase = kv * 64;
            if (kbase > wq0 + 31) continue;   // wave fully beyond causal reach

            // K fragments: loaded once, shared by both q-blocks
            bf16x8 kf[4][2];
            #pragma unroll
            for (int n = 0; n < 4; n++)
                #pragma unroll
                for (int kd = 0; kd < 2; kd++) {
                    int row = n * 16 + q16;
                    int a = row * 128 + (kd * 64 + 16 * g);
                    a ^= ((row & 7) << 4);
                    kf[n][kd] = *(const bf16x8*)((const char*)Ks + a);
                }

            // S^T = K Q^T for both q-blocks
            f32x4 sf[2][4] = {};
            #pragma unroll
            for (int n = 0; n < 4; n++)
                #pragma unroll
                for (int kd = 0; kd < 2; kd++) {
                    sf[0][n] = __builtin_amdgcn_mfma_f32_16x16x32_bf16(
                        kf[n][kd], qf[0][kd], sf[0][n], 0, 0, 0);
                    sf[1][n] = __builtin_amdgcn_mfma_f32_16x16x32_bf16(
                        kf[n][kd], qf[1][kd], sf[1][n], 0, 0, 0);
                }

            // softmax (exp2 domain) per q-block
            #pragma unroll
            for (int qb2 = 0; qb2 < 2; qb2++) {
                const int wqb = wq0 + 16 * qb2 + q16;
                const bool partial = (kbase + 63 > wq0 + 16 * qb2);
                float p[4][4];
                #pragma unroll
                for (int n = 0; n < 4; n++)
                    #pragma unroll
                    for (int r = 0; r < 4; r++) {
                        float v = sf[qb2][n][r];
                        if (partial) {
                            int kg = kbase + n * 16 + 4 * g + r;
                            if (kg > wqb) v = -1.0e30f;
                        }
                        p[n][r] = v;
                    }
                float mx0 = fmaxf(fmaxf(p[0][0], p[0][1]), fmaxf(p[0][2], p[0][3]));
                float mx1 = fmaxf(fmaxf(p[1][0], p[1][1]), fmaxf(p[1][2], p[1][3]));
                float mx2 = fmaxf(fmaxf(p[2][0], p[2][1]), fmaxf(p[2][2], p[2][3]));
                float mx3 = fmaxf(fmaxf(p[3][0], p[3][1]), fmaxf(p[3][2], p[3][3]));
                float mx = fmaxf(fmaxf(mx0, mx1), fmaxf(mx2, mx3));
                mx = fmaxf(mx, __shfl_xor(mx, 16));
                mx = fmaxf(mx, __shfl_xor(mx, 32));
                // defer-max: 11.5 bits = 8 nats
                if (__any(mx > m_run[qb2] + 11.5f)) {
                    float mn = fmaxf(m_run[qb2], mx);
                    float corr = exp2_fast(m_run[qb2] - mn);
                    m_run[qb2] = mn;
                    l_run[qb2] *= corr;
                    #pragma unroll
                    for (int nf = 0; nf < 4; nf++) {
                        f32x4 o4 = of[qb2][nf];
                        o4[0] *= corr; o4[1] *= corr; o4[2] *= corr; o4[3] *= corr;
                        of[qb2][nf] = o4;
                    }
                }
                float ps = 0.f;
                #pragma unroll
                for (int n = 0; n < 4; n++)
                    #pragma unroll
                    for (int r = 0; r < 4; r++) {
                        p[n][r] = exp2_fast(p[n][r] - m_run[qb2]);
                        ps += p[n][r];
                    }
                ps += __shfl_xor(ps, 16);
                ps += __shfl_xor(ps, 32);
                l_run[qb2] += ps;
                unsigned int* pr = &Pw[wave][16 * qb2 + q16][0];
                #pragma unroll
                for (int n = 0; n < 4; n++) {
                    pr[8 * n + 2 * g + 0] = cvt_pk_bf16(p[n][0], p[n][1]);
                    pr[8 * n + 2 * g + 1] = cvt_pk_bf16(p[n][2], p[n][3]);
                }
            }

            // O^T += V^T P^T ; V fragments shared by both q-blocks
            #pragma unroll
            for (int kbk = 0; kbk < 2; kbk++) {
                bf16x8 pfr[2];
                #pragma unroll
                for (int qb2 = 0; qb2 < 2; qb2++) {
                    const unsigned int* pr = &Pw[wave][16 * qb2 + q16][0];
                    uint4 pu;
                    pu.x = pr[16 * kbk + 4 * g + 0];
                    pu.y = pr[16 * kbk + 4 * g + 1];
                    pu.z = pr[16 * kbk + 4 * g + 2];
                    pu.w = pr[16 * kbk + 4 * g + 3];
                    pfr[qb2] = __builtin_bit_cast(bf16x8, pu);
                }
                #pragma unroll
                for (int nf = 0; nf < 4; nf++) {
                    const int d = nf * 16 + q16;
                    int a = (d << 7) + (kbk * 64 + 16 * g);
                    a ^= (((d & 7) ^ ((d >> 3) & 7)) << 4);
                    bf16x8 vf = *(const bf16x8*)((const char*)Vt + a);
                    of[0][nf] = __builtin_amdgcn_mfma_f32_16x16x32_bf16(
                        vf, pfr[0], of[0][nf], 0, 0, 0);
                    of[1][nf] = __builtin_amdgcn_mfma_f32_16x16x32_bf16(
                        vf, pfr[1], of[1][nf], 0, 0, 0);
                }
            }
        }

        // epilogue: of[qb][nf][r] = O[q][d = nf*16 + 4g + r]
        #pragma unroll
        for (int qb2 = 0; qb2 < 2; qb2++) {
            float rl = 1.f / l_run[qb2];
            const size_t orow = (size_t)b * NT + q0 + wave * 32 + 16 * qb2 + q16;
            #pragma unroll
            for (int nf = 0; nf < 4; nf++) {
                ushort4 o4;
                o4.x = f2bf(of[qb2][nf][0] * rl);
                o4.y = f2bf(of[qb2][nf][1] * rl);
                o4.z = f2bf(of[qb2][nf][2] * rl);
                o4.w = f2bf(of[qb2][nf][3] * rl);
                *(ushort4*)(out + orow * ND + h * NHD + nf * 16 + 4 * g) = o4;
            }
        }
    }
}

// ---------------------------------------------------------------------------
extern "C" void kernel_launch(void* const* d_in, const int* in_sizes, int n_in,
                              void* d_out, int out_size, void* d_ws, size_t ws_size,
                              hipStream_t stream) {
    const float* x     = (const float*)d_in[0];
    const float* ln1_g = (const float*)d_in[1];
    const float* ln1_b = (const float*)d_in[2];
    const float* ln2_g = (const float*)d_in[3];
    const float* ln2_b = (const float*)d_in[4];
    const float* Wq    = (const float*)d_in[5];
    const float* Wk    = (const float*)d_in[6];
    const float* Wv    = (const float*)d_in[7];
    const float* Wo    = (const float*)d_in[8];
    const float* bo    = (const float*)d_in[9];
    const float* W1    = (const float*)d_in[10];
    const float* b1    = (const float*)d_in[11];
    const float* W2    = (const float*)d_in[12];
    const float* b2    = (const float*)d_in[13];
    float* outp = (float*)d_out;

    char* w = (char*)d_ws;
    ushort_t* Wqkv_t = (ushort_t*)(w);                    // 6 MiB  (3072x1024)
    ushort_t* Wo_t   = (ushort_t*)(w + 6291456);          // 2 MiB  (1024x1024)
    ushort_t* W1_t   = (ushort_t*)(w + 8388608);          // 8 MiB  (4096x1024)
    ushort_t* W2_t   = (ushort_t*)(w + 16777216);         // 8 MiB  (1024x4096)
    ushort_t* xn     = (ushort_t*)(w + 25165824);         // 16 MiB (8192x1024), also hn
    ushort_t* qkv    = (ushort_t*)(w + 41943040);         // 48 MiB (8192x3072)
    ushort_t* attn_o = qkv + (size_t)MTOK * 3072;         // 16 MiB (8192x1024)
    ushort_t* ff1    = qkv;                               // 64 MiB (8192x4096) reuse
    float*    hbuf   = (float*)(w + 41943040 + 67108864); // 32 MiB (8192x1024 f32)

    dim3 tb(32, 8);
    transpose_qkv_to_bf16<<<dim3(2, 32, 48), tb, 0, stream>>>(Wq, Wk, Wv, Wqkv_t);
    transpose_to_bf16<<<dim3(32, 32), tb, 0, stream>>>(Wo, Wo_t, 1024, 1024);
    transpose_to_bf16<<<dim3(128, 32), tb, 0, stream>>>(W1, W1_t, 1024, 4096);
    transpose_to_bf16<<<dim3(32, 128), tb, 0, stream>>>(W2, W2_t, 4096, 1024);

    layernorm_to_bf16<<<MTOK, 256, 0, stream>>>(x, ln1_g, ln1_b, xn);

    gemm_bf16<false, false, false, false><<<dim3(24, 64), 256, 0, stream>>>(
        xn, Wqkv_t, nullptr, nullptr, qkv, MTOK, 3072, 1024);

    attn_kernel<<<dim3(4, 64), 512, 0, stream>>>(qkv, attn_o);

    gemm_bf16<true, false, true, true><<<dim3(8, 64), 256, 0, stream>>>(
        attn_o, Wo_t, bo, x, hbuf, MTOK, 1024, 1024);

    layernorm_to_bf16<<<MTOK, 256, 0, stream>>>(hbuf, ln2_g, ln2_b, xn);

    gemm_bf16<true, true, false, false><<<dim3(32, 64), 256, 0, stream>>>(
        xn, W1_t, b1, nullptr, ff1, MTOK, NF, 1024);

    gemm_bf16<true, false, true, true><<<dim3(8, 64), 256, 0, stream>>>(
        ff1, W2_t, b2, hbuf, outp, MTOK, 1024, NF);
}

// Round 6
// 398.915 us; speedup vs baseline: 1.4720x; 1.0037x over previous
//
#include <hip/hip_runtime.h>
#include <hip/hip_bf16.h>

#define NB 4
#define NT 2048
#define ND 1024
#define NH 16
#define NHD 64
#define NF 4096
#define MTOK (NB*NT)  // 8192

typedef float f32x4 __attribute__((ext_vector_type(4)));
typedef __bf16 bf16x8 __attribute__((ext_vector_type(8)));
typedef short s16x8 __attribute__((ext_vector_type(8)));
typedef short s16x4v __attribute__((ext_vector_type(4)));
typedef unsigned short ushort_t;

__device__ inline ushort_t f2bf(float f) {
    unsigned int u = __builtin_bit_cast(unsigned int, f);
    unsigned int r = (u + 0x7FFFu + ((u >> 16) & 1u)) >> 16;
    return (ushort_t)r;
}

__device__ __forceinline__ void async_load16(const void* g, void* l) {
    __builtin_amdgcn_global_load_lds(
        (const __attribute__((address_space(1))) void*)g,
        (__attribute__((address_space(3))) void*)l, 16, 0, 0);
}

__device__ __forceinline__ unsigned int cvt_pk_bf16(float lo, float hi) {
    unsigned int r;
    asm("v_cvt_pk_bf16_f32 %0, %1, %2" : "=v"(r) : "v"(lo), "v"(hi));
    return r;
}

__device__ __forceinline__ float exp2_fast(float x) {
    float r;
    asm("v_exp_f32 %0, %1" : "=v"(r) : "v"(x));
    return r;
}

// ---------------------------------------------------------------------------
// Transpose-convert: src fp32 (R x C) row-major -> dst bf16 (C x R) row-major
// ---------------------------------------------------------------------------
__global__ __launch_bounds__(256)
void transpose_to_bf16(const float* __restrict__ src, ushort_t* __restrict__ dst,
                       int R, int C) {
    __shared__ float tile[32][33];
    int c0 = blockIdx.x * 32, r0 = blockIdx.y * 32;
    #pragma unroll
    for (int i = 0; i < 32; i += 8)
        tile[threadIdx.y + i][threadIdx.x] =
            src[(size_t)(r0 + threadIdx.y + i) * C + c0 + threadIdx.x];
    __syncthreads();
    #pragma unroll
    for (int i = 0; i < 32; i += 8)
        dst[(size_t)(c0 + threadIdx.y + i) * R + r0 + threadIdx.x] =
            f2bf(tile[threadIdx.x][threadIdx.y + i]);
}

// QKV weights: Wq/Wk/Wv are (H, D, HD). Build Bt (3072 x 1024) bf16.
// Wq pre-scaled by (1/32)*log2(e): QK^T scores come out in exp2 domain.
__global__ __launch_bounds__(256)
void transpose_qkv_to_bf16(const float* __restrict__ Wq, const float* __restrict__ Wk,
                           const float* __restrict__ Wv, ushort_t* __restrict__ dst) {
    __shared__ float tile[32][33];
    int z = blockIdx.z;            // 0..47
    int w = z >> 4, h = z & 15;
    const float* src = (w == 0 ? Wq : (w == 1 ? Wk : Wv)) + (size_t)h * ND * NHD;
    const float sc = (w == 0) ? 0.03125f * 1.44269504f : 1.0f;
    ushort_t* out = dst + ((size_t)w * ND + h * NHD) * ND;
    int c0 = blockIdx.x * 32, r0 = blockIdx.y * 32;
    #pragma unroll
    for (int i = 0; i < 32; i += 8)
        tile[threadIdx.y + i][threadIdx.x] =
            src[(size_t)(r0 + threadIdx.y + i) * NHD + c0 + threadIdx.x];
    __syncthreads();
    #pragma unroll
    for (int i = 0; i < 32; i += 8)
        out[(size_t)(c0 + threadIdx.y + i) * ND + r0 + threadIdx.x] =
            f2bf(tile[threadIdx.x][threadIdx.y + i] * sc);
}

// ---------------------------------------------------------------------------
// LayerNorm (rows of 1024 fp32) -> bf16 out
// ---------------------------------------------------------------------------
__global__ __launch_bounds__(256)
void layernorm_to_bf16(const float* __restrict__ x, const float* __restrict__ g,
                       const float* __restrict__ bvec, ushort_t* __restrict__ out) {
    int row = blockIdx.x;
    const float4* xr = (const float4*)(x + (size_t)row * ND);
    float4 v = xr[threadIdx.x];
    float s = v.x + v.y + v.z + v.w;
    float s2 = v.x * v.x + v.y * v.y + v.z * v.z + v.w * v.w;
    #pragma unroll
    for (int o = 32; o >= 1; o >>= 1) {
        s += __shfl_xor(s, o);
        s2 += __shfl_xor(s2, o);
    }
    __shared__ float red[8];
    int wave = threadIdx.x >> 6, lane = threadIdx.x & 63;
    if (lane == 0) { red[wave] = s; red[4 + wave] = s2; }
    __syncthreads();
    float ts = red[0] + red[1] + red[2] + red[3];
    float ts2 = red[4] + red[5] + red[6] + red[7];
    float mu = ts * (1.f / ND);
    float var = ts2 * (1.f / ND) - mu * mu;
    float rs = rsqrtf(var + 1e-5f);
    float4 gv = ((const float4*)g)[threadIdx.x];
    float4 bv = ((const float4*)bvec)[threadIdx.x];
    ushort4 o4;
    o4.x = f2bf((v.x - mu) * rs * gv.x + bv.x);
    o4.y = f2bf((v.y - mu) * rs * gv.y + bv.y);
    o4.z = f2bf((v.z - mu) * rs * gv.z + bv.z);
    o4.w = f2bf((v.w - mu) * rs * gv.w + bv.w);
    ((ushort4*)(out + (size_t)row * ND))[threadIdx.x] = o4;
}

// ---------------------------------------------------------------------------
// GEMM: C[M,N] = A[M,K] (bf16) * Bt[N,K]^T (bf16)  (+bias, relu, +res)
// 128x128 tile, BK=64, 4 waves, mfma 16x16x32, global_load_lds staging,
// bijective XCD-aware block swizzle (nwg % 8 == 0 for all launches).
// ---------------------------------------------------------------------------
template<bool HAS_BIAS, bool RELU, bool HAS_RES, bool OUT_F32>
__global__ __launch_bounds__(256)
void gemm_bf16(const ushort_t* __restrict__ A, const ushort_t* __restrict__ Bt,
               const float* __restrict__ bias, const float* __restrict__ res,
               void* __restrict__ outp, int M, int N, int K) {
    __shared__ __align__(16) ushort_t As[128 * 64];
    __shared__ __align__(16) ushort_t Bs[128 * 64];
    const int t = threadIdx.x;
    const int wave = t >> 6, lane = t & 63;
    int wid = blockIdx.y * gridDim.x + blockIdx.x;
    const int cpx = (gridDim.x * gridDim.y) >> 3;
    wid = (wid & 7) * cpx + (wid >> 3);
    const int m0 = (wid / gridDim.x) * 128, n0 = (wid % gridDim.x) * 128;
    const int wr = (wave >> 1) * 64, wc = (wave & 1) * 64;
    const int rw = lane >> 3;            // row within the wave's 8-row group
    const int ck = lane & 7;             // 16B chunk within the 128B row
    const int srcCol = (ck ^ rw) * 8;    // pre-swizzled source column (ushorts)
    f32x4 acc[4][4] = {};

    const ushort_t* Abase = A + (size_t)m0 * K + srcCol;
    const ushort_t* Bbase = Bt + (size_t)n0 * K + srcCol;

    for (int kt = 0; kt < K; kt += 64) {
        __syncthreads();
        #pragma unroll
        for (int c = 0; c < 4; c++) {
            const int rowbase = c * 32 + wave * 8;          // wave-uniform
            const size_t goff = (size_t)(rowbase + rw) * K + kt;
            async_load16(Abase + goff, As + rowbase * 64);
            async_load16(Bbase + goff, Bs + rowbase * 64);
        }
        __syncthreads();
        #pragma unroll
        for (int ks = 0; ks < 2; ks++) {
            bf16x8 af[4], bfr[4];
            #pragma unroll
            for (int m = 0; m < 4; m++) {
                int row = wr + m * 16 + (lane & 15);
                int a = row * 128 + (ks * 32 + 8 * (lane >> 4)) * 2;
                a ^= ((row & 7) << 4);
                af[m] = *(const bf16x8*)((const char*)As + a);
            }
            #pragma unroll
            for (int n = 0; n < 4; n++) {
                int row = wc + n * 16 + (lane & 15);
                int a = row * 128 + (ks * 32 + 8 * (lane >> 4)) * 2;
                a ^= ((row & 7) << 4);
                bfr[n] = *(const bf16x8*)((const char*)Bs + a);
            }
            #pragma unroll
            for (int m = 0; m < 4; m++)
                #pragma unroll
                for (int n = 0; n < 4; n++)
                    acc[m][n] = __builtin_amdgcn_mfma_f32_16x16x32_bf16(
                        af[m], bfr[n], acc[m][n], 0, 0, 0);
        }
    }

    const int gr0 = m0 + wr + (lane >> 4) * 4;
    const int gc0 = n0 + wc + (lane & 15);
    #pragma unroll
    for (int mf = 0; mf < 4; mf++) {
        #pragma unroll
        for (int nf = 0; nf < 4; nf++) {
            int col = gc0 + nf * 16;
            float bb = 0.f;
            if constexpr (HAS_BIAS) bb = bias[col];
            #pragma unroll
            for (int r = 0; r < 4; r++) {
                int row = gr0 + mf * 16 + r;
                float v = acc[mf][nf][r] + bb;
                if constexpr (RELU) v = fmaxf(v, 0.f);
                if constexpr (HAS_RES) v += res[(size_t)row * N + col];
                if constexpr (OUT_F32)
                    ((float*)outp)[(size_t)row * N + col] = v;
                else
                    ((ushort_t*)outp)[(size_t)row * N + col] = f2bf(v);
            }
        }
    }
}

// ---------------------------------------------------------------------------
// Causal flash attention. QBLK=128: 4 waves x 32 q-rows (2 q-col-blocks per
// wave, K/V fragments reused by both -> 1:2 LDS-read:MFMA). KVBLK=64.
// 256-thread blocks, grid (8,64)=512 = exactly 2 independent blocks/CU
// (restores barrier/staging overlap lost in round 5's 1-block/CU layout).
// Pairs (qt, 15-qt): every block exactly 34 kv iterations. exp2-domain
// softmax (log2e folded into Wq). XCD swizzle co-locates each bh's blocks.
// ---------------------------------------------------------------------------
__global__ __launch_bounds__(256)
void attn_kernel(const ushort_t* __restrict__ qkv, ushort_t* __restrict__ out) {
    __shared__ __align__(16) ushort_t Ks[64 * 64];   // linear, XOR-swizzle on read
    __shared__ __align__(16) ushort_t Vt[64 * 64];   // d-major, XOR-swizzled
    __shared__ unsigned int Pw[4][32][35];           // per-wave P words
    const int L = blockIdx.y * gridDim.x + blockIdx.x;   // grid (8,64) -> 512
    const int xcd = L & 7, kk = L >> 3;              // kk 0..63 per XCD
    const int bh = ((kk & 7) << 3) | xcd;            // 8 pair-blocks of bh -> one XCD
    const int pairIdx = kk >> 3;                     // 0..7
    const int b = bh >> 4, h = bh & 15;
    const int t = threadIdx.x, wave = t >> 6, lane = t & 63;
    const int g = lane >> 4, q16 = lane & 15;
    const size_t base = ((size_t)b * NT) * 3072 + h * NHD;
    const ushort_t* qp_base = qkv + base;
    const ushort_t* kb = qkv + base + 1024;
    const ushort_t* vb = qkv + base + 2048;
    // K staging: 2 x global_load_lds per thread; HW dest = base + lane*16
    const int krw = lane >> 3, kck = lane & 7;
    const int ksrc = (kck ^ krw) * 8;                // pre-swizzled source column
    // V staging: thread handles 8 d-values x 2 k
    const int vkp = t >> 3, vdg = t & 7;

    for (int half = 0; half < 2; half++) {
        const int qt = half ? (15 - pairIdx) : pairIdx;
        const int q0 = qt * 128;
        const int wq0 = q0 + wave * 32;
        bf16x8 qf[2][2];
        #pragma unroll
        for (int qb2 = 0; qb2 < 2; qb2++) {
            const ushort_t* qp = qp_base + (size_t)(wq0 + 16 * qb2 + q16) * 3072 + 8 * g;
            qf[qb2][0] = *(const bf16x8*)qp;
            qf[qb2][1] = *(const bf16x8*)(qp + 32);
        }
        f32x4 of[2][4] = {};
        float m_run[2] = {-1.0e30f, -1.0e30f};
        float l_run[2] = {0.f, 0.f};
        const int nkv = 2 * qt + 2;

        for (int kv = 0; kv < nkv; ++kv) {
            __syncthreads();
            // K: two global_load_lds per thread (8KB tile, 32 rows per call)
            #pragma unroll
            for (int c = 0; c < 2; c++) {
                const int rowbase = c * 32 + wave * 8;      // wave-uniform
                async_load16(kb + (size_t)(kv * 64 + rowbase + krw) * 3072 + ksrc,
                             Ks + rowbase * 64);
            }
            // V: register transpose to d-major, XOR-swizzled
            {
                const ushort_t* vp = vb + (size_t)(kv * 64 + 2 * vkp) * 3072 + vdg * 8;
                s16x8 v0 = *(const s16x8*)vp;
                s16x8 v1 = *(const s16x8*)(vp + 3072);
                #pragma unroll
                for (int dd = 0; dd < 8; dd++) {
                    int d = vdg * 8 + dd;
                    unsigned int wv = (unsigned int)(ushort_t)v0[dd] |
                                      ((unsigned int)(ushort_t)v1[dd] << 16);
                    int a = (d << 7) + (vkp << 2);
                    a ^= (((d & 7) ^ ((d >> 3) & 7)) << 4);
                    *(unsigned int*)((char*)Vt + a) = wv;
                }
            }
            __syncthreads();

            const int kbase = kv * 64;
            if (kbase > wq0 + 31) continue;   // wave fully beyond causal reach

            // K fragments: loaded once, shared by both q-blocks
            bf16x8 kf[4][2];
            #pragma unroll
            for (int n = 0; n < 4; n++)
                #pragma unroll
                for (int kd = 0; kd < 2; kd++) {
                    int row = n * 16 + q16;
                    int a = row * 128 + (kd * 64 + 16 * g);
                    a ^= ((row & 7) << 4);
                    kf[n][kd] = *(const bf16x8*)((const char*)Ks + a);
                }

            // S^T = K Q^T for both q-blocks
            f32x4 sf[2][4] = {};
            #pragma unroll
            for (int n = 0; n < 4; n++)
                #pragma unroll
                for (int kd = 0; kd < 2; kd++) {
                    sf[0][n] = __builtin_amdgcn_mfma_f32_16x16x32_bf16(
                        kf[n][kd], qf[0][kd], sf[0][n], 0, 0, 0);
                    sf[1][n] = __builtin_amdgcn_mfma_f32_16x16x32_bf16(
                        kf[n][kd], qf[1][kd], sf[1][n], 0, 0, 0);
                }

            // softmax (exp2 domain) per q-block
            #pragma unroll
            for (int qb2 = 0; qb2 < 2; qb2++) {
                const int wqb = wq0 + 16 * qb2 + q16;
                const bool partial = (kbase + 63 > wq0 + 16 * qb2);
                float p[4][4];
                #pragma unroll
                for (int n = 0; n < 4; n++)
                    #pragma unroll
                    for (int r = 0; r < 4; r++) {
                        float v = sf[qb2][n][r];
                        if (partial) {
                            int kg = kbase + n * 16 + 4 * g + r;
                            if (kg > wqb) v = -1.0e30f;
                        }
                        p[n][r] = v;
                    }
                float mx0 = fmaxf(fmaxf(p[0][0], p[0][1]), fmaxf(p[0][2], p[0][3]));
                float mx1 = fmaxf(fmaxf(p[1][0], p[1][1]), fmaxf(p[1][2], p[1][3]));
                float mx2 = fmaxf(fmaxf(p[2][0], p[2][1]), fmaxf(p[2][2], p[2][3]));
                float mx3 = fmaxf(fmaxf(p[3][0], p[3][1]), fmaxf(p[3][2], p[3][3]));
                float mx = fmaxf(fmaxf(mx0, mx1), fmaxf(mx2, mx3));
                mx = fmaxf(mx, __shfl_xor(mx, 16));
                mx = fmaxf(mx, __shfl_xor(mx, 32));
                // defer-max: 11.5 bits = 8 nats
                if (__any(mx > m_run[qb2] + 11.5f)) {
                    float mn = fmaxf(m_run[qb2], mx);
                    float corr = exp2_fast(m_run[qb2] - mn);
                    m_run[qb2] = mn;
                    l_run[qb2] *= corr;
                    #pragma unroll
                    for (int nf = 0; nf < 4; nf++) {
                        f32x4 o4 = of[qb2][nf];
                        o4[0] *= corr; o4[1] *= corr; o4[2] *= corr; o4[3] *= corr;
                        of[qb2][nf] = o4;
                    }
                }
                float ps = 0.f;
                #pragma unroll
                for (int n = 0; n < 4; n++)
                    #pragma unroll
                    for (int r = 0; r < 4; r++) {
                        p[n][r] = exp2_fast(p[n][r] - m_run[qb2]);
                        ps += p[n][r];
                    }
                ps += __shfl_xor(ps, 16);
                ps += __shfl_xor(ps, 32);
                l_run[qb2] += ps;
                unsigned int* pr = &Pw[wave][16 * qb2 + q16][0];
                #pragma unroll
                for (int n = 0; n < 4; n++) {
                    pr[8 * n + 2 * g + 0] = cvt_pk_bf16(p[n][0], p[n][1]);
                    pr[8 * n + 2 * g + 1] = cvt_pk_bf16(p[n][2], p[n][3]);
                }
            }

            // O^T += V^T P^T ; V fragments shared by both q-blocks
            #pragma unroll
            for (int kbk = 0; kbk < 2; kbk++) {
                bf16x8 pfr[2];
                #pragma unroll
                for (int qb2 = 0; qb2 < 2; qb2++) {
                    const unsigned int* pr = &Pw[wave][16 * qb2 + q16][0];
                    uint4 pu;
                    pu.x = pr[16 * kbk + 4 * g + 0];
                    pu.y = pr[16 * kbk + 4 * g + 1];
                    pu.z = pr[16 * kbk + 4 * g + 2];
                    pu.w = pr[16 * kbk + 4 * g + 3];
                    pfr[qb2] = __builtin_bit_cast(bf16x8, pu);
                }
                #pragma unroll
                for (int nf = 0; nf < 4; nf++) {
                    const int d = nf * 16 + q16;
                    int a = (d << 7) + (kbk * 64 + 16 * g);
                    a ^= (((d & 7) ^ ((d >> 3) & 7)) << 4);
                    bf16x8 vf = *(const bf16x8*)((const char*)Vt + a);
                    of[0][nf] = __builtin_amdgcn_mfma_f32_16x16x32_bf16(
                        vf, pfr[0], of[0][nf], 0, 0, 0);
                    of[1][nf] = __builtin_amdgcn_mfma_f32_16x16x32_bf16(
                        vf, pfr[1], of[1][nf], 0, 0, 0);
                }
            }
        }

        // epilogue: of[qb][nf][r] = O[q][d = nf*16 + 4g + r]
        #pragma unroll
        for (int qb2 = 0; qb2 < 2; qb2++) {
            float rl = 1.f / l_run[qb2];
            const size_t orow = (size_t)b * NT + q0 + wave * 32 + 16 * qb2 + q16;
            #pragma unroll
            for (int nf = 0; nf < 4; nf++) {
                ushort4 o4;
                o4.x = f2bf(of[qb2][nf][0] * rl);
                o4.y = f2bf(of[qb2][nf][1] * rl);
                o4.z = f2bf(of[qb2][nf][2] * rl);
                o4.w = f2bf(of[qb2][nf][3] * rl);
                *(ushort4*)(out + orow * ND + h * NHD + nf * 16 + 4 * g) = o4;
            }
        }
    }
}

// ---------------------------------------------------------------------------
extern "C" void kernel_launch(void* const* d_in, const int* in_sizes, int n_in,
                              void* d_out, int out_size, void* d_ws, size_t ws_size,
                              hipStream_t stream) {
    const float* x     = (const float*)d_in[0];
    const float* ln1_g = (const float*)d_in[1];
    const float* ln1_b = (const float*)d_in[2];
    const float* ln2_g = (const float*)d_in[3];
    const float* ln2_b = (const float*)d_in[4];
    const float* Wq    = (const float*)d_in[5];
    const float* Wk    = (const float*)d_in[6];
    const float* Wv    = (const float*)d_in[7];
    const float* Wo    = (const float*)d_in[8];
    const float* bo    = (const float*)d_in[9];
    const float* W1    = (const float*)d_in[10];
    const float* b1    = (const float*)d_in[11];
    const float* W2    = (const float*)d_in[12];
    const float* b2    = (const float*)d_in[13];
    float* outp = (float*)d_out;

    char* w = (char*)d_ws;
    ushort_t* Wqkv_t = (ushort_t*)(w);                    // 6 MiB  (3072x1024)
    ushort_t* Wo_t   = (ushort_t*)(w + 6291456);          // 2 MiB  (1024x1024)
    ushort_t* W1_t   = (ushort_t*)(w + 8388608);          // 8 MiB  (4096x1024)
    ushort_t* W2_t   = (ushort_t*)(w + 16777216);         // 8 MiB  (1024x4096)
    ushort_t* xn     = (ushort_t*)(w + 25165824);         // 16 MiB (8192x1024), also hn
    ushort_t* qkv    = (ushort_t*)(w + 41943040);         // 48 MiB (8192x3072)
    ushort_t* attn_o = qkv + (size_t)MTOK * 3072;         // 16 MiB (8192x1024)
    ushort_t* ff1    = qkv;                               // 64 MiB (8192x4096) reuse
    float*    hbuf   = (float*)(w + 41943040 + 67108864); // 32 MiB (8192x1024 f32)

    dim3 tb(32, 8);
    transpose_qkv_to_bf16<<<dim3(2, 32, 48), tb, 0, stream>>>(Wq, Wk, Wv, Wqkv_t);
    transpose_to_bf16<<<dim3(32, 32), tb, 0, stream>>>(Wo, Wo_t, 1024, 1024);
    transpose_to_bf16<<<dim3(128, 32), tb, 0, stream>>>(W1, W1_t, 1024, 4096);
    transpose_to_bf16<<<dim3(32, 128), tb, 0, stream>>>(W2, W2_t, 4096, 1024);

    layernorm_to_bf16<<<MTOK, 256, 0, stream>>>(x, ln1_g, ln1_b, xn);

    gemm_bf16<false, false, false, false><<<dim3(24, 64), 256, 0, stream>>>(
        xn, Wqkv_t, nullptr, nullptr, qkv, MTOK, 3072, 1024);

    attn_kernel<<<dim3(8, 64), 256, 0, stream>>>(qkv, attn_o);

    gemm_bf16<true, false, true, true><<<dim3(8, 64), 256, 0, stream>>>(
        attn_o, Wo_t, bo, x, hbuf, MTOK, 1024, 1024);

    layernorm_to_bf16<<<MTOK, 256, 0, stream>>>(hbuf, ln2_g, ln2_b, xn);

    gemm_bf16<true, true, false, false><<<dim3(32, 64), 256, 0, stream>>>(
        xn, W1_t, b1, nullptr, ff1, MTOK, NF, 1024);

    gemm_bf16<true, false, true, true><<<dim3(8, 64), 256, 0, stream>>>(
        ff1, W2_t, b2, hbuf, outp, MTOK, 1024, NF);
}

// Round 7
// 388.920 us; speedup vs baseline: 1.5098x; 1.0257x over previous
//
#include <hip/hip_runtime.h>
#include <hip/hip_bf16.h>

#define NB 4
#define NT 2048
#define ND 1024
#define NH 16
#define NHD 64
#define NF 4096
#define MTOK (NB*NT)  // 8192

typedef float f32x4 __attribute__((ext_vector_type(4)));
typedef __bf16 bf16x8 __attribute__((ext_vector_type(8)));
typedef short s16x8 __attribute__((ext_vector_type(8)));
typedef unsigned short ushort_t;

__device__ inline ushort_t f2bf(float f) {
    unsigned int u = __builtin_bit_cast(unsigned int, f);
    unsigned int r = (u + 0x7FFFu + ((u >> 16) & 1u)) >> 16;
    return (ushort_t)r;
}

__device__ __forceinline__ void async_load16(const void* g, void* l) {
    __builtin_amdgcn_global_load_lds(
        (const __attribute__((address_space(1))) void*)g,
        (__attribute__((address_space(3))) void*)l, 16, 0, 0);
}

__device__ __forceinline__ unsigned int cvt_pk_bf16(float lo, float hi) {
    unsigned int r;
    asm("v_cvt_pk_bf16_f32 %0, %1, %2" : "=v"(r) : "v"(lo), "v"(hi));
    return r;
}

__device__ __forceinline__ float exp2_fast(float x) {
    float r;
    asm("v_exp_f32 %0, %1" : "=v"(r) : "v"(x));
    return r;
}

// ---------------------------------------------------------------------------
// Transpose-convert: src fp32 (R x C) row-major -> dst bf16 (C x R) row-major
// ---------------------------------------------------------------------------
__global__ __launch_bounds__(256)
void transpose_to_bf16(const float* __restrict__ src, ushort_t* __restrict__ dst,
                       int R, int C) {
    __shared__ float tile[32][33];
    int c0 = blockIdx.x * 32, r0 = blockIdx.y * 32;
    #pragma unroll
    for (int i = 0; i < 32; i += 8)
        tile[threadIdx.y + i][threadIdx.x] =
            src[(size_t)(r0 + threadIdx.y + i) * C + c0 + threadIdx.x];
    __syncthreads();
    #pragma unroll
    for (int i = 0; i < 32; i += 8)
        dst[(size_t)(c0 + threadIdx.y + i) * R + r0 + threadIdx.x] =
            f2bf(tile[threadIdx.x][threadIdx.y + i]);
}

// QKV weights: Wq/Wk/Wv are (H, D, HD). Build Bt (3072 x 1024) bf16.
// Wq pre-scaled by (1/32)*log2(e): QK^T scores come out in exp2 domain.
__global__ __launch_bounds__(256)
void transpose_qkv_to_bf16(const float* __restrict__ Wq, const float* __restrict__ Wk,
                           const float* __restrict__ Wv, ushort_t* __restrict__ dst) {
    __shared__ float tile[32][33];
    int z = blockIdx.z;            // 0..47
    int w = z >> 4, h = z & 15;
    const float* src = (w == 0 ? Wq : (w == 1 ? Wk : Wv)) + (size_t)h * ND * NHD;
    const float sc = (w == 0) ? 0.03125f * 1.44269504f : 1.0f;
    ushort_t* out = dst + ((size_t)w * ND + h * NHD) * ND;
    int c0 = blockIdx.x * 32, r0 = blockIdx.y * 32;
    #pragma unroll
    for (int i = 0; i < 32; i += 8)
        tile[threadIdx.y + i][threadIdx.x] =
            src[(size_t)(r0 + threadIdx.y + i) * NHD + c0 + threadIdx.x];
    __syncthreads();
    #pragma unroll
    for (int i = 0; i < 32; i += 8)
        out[(size_t)(c0 + threadIdx.y + i) * ND + r0 + threadIdx.x] =
            f2bf(tile[threadIdx.x][threadIdx.y + i] * sc);
}

// ---------------------------------------------------------------------------
// LayerNorm (rows of 1024 fp32) -> bf16 out
// ---------------------------------------------------------------------------
__global__ __launch_bounds__(256)
void layernorm_to_bf16(const float* __restrict__ x, const float* __restrict__ g,
                       const float* __restrict__ bvec, ushort_t* __restrict__ out) {
    int row = blockIdx.x;
    const float4* xr = (const float4*)(x + (size_t)row * ND);
    float4 v = xr[threadIdx.x];
    float s = v.x + v.y + v.z + v.w;
    float s2 = v.x * v.x + v.y * v.y + v.z * v.z + v.w * v.w;
    #pragma unroll
    for (int o = 32; o >= 1; o >>= 1) {
        s += __shfl_xor(s, o);
        s2 += __shfl_xor(s2, o);
    }
    __shared__ float red[8];
    int wave = threadIdx.x >> 6, lane = threadIdx.x & 63;
    if (lane == 0) { red[wave] = s; red[4 + wave] = s2; }
    __syncthreads();
    float ts = red[0] + red[1] + red[2] + red[3];
    float ts2 = red[4] + red[5] + red[6] + red[7];
    float mu = ts * (1.f / ND);
    float var = ts2 * (1.f / ND) - mu * mu;
    float rs = rsqrtf(var + 1e-5f);
    float4 gv = ((const float4*)g)[threadIdx.x];
    float4 bv = ((const float4*)bvec)[threadIdx.x];
    ushort4 o4;
    o4.x = f2bf((v.x - mu) * rs * gv.x + bv.x);
    o4.y = f2bf((v.y - mu) * rs * gv.y + bv.y);
    o4.z = f2bf((v.z - mu) * rs * gv.z + bv.z);
    o4.w = f2bf((v.w - mu) * rs * gv.w + bv.w);
    ((ushort4*)(out + (size_t)row * ND))[threadIdx.x] = o4;
}

// ---------------------------------------------------------------------------
// Pipelined GEMM: C[M,N] = A[M,K] * Bt[N,K]^T (bf16), 256 x BN tile, BK=64,
// 512 threads (8 waves, 2M x 4N), double-buffered K-tile slots, counted-vmcnt
// prefetch pipeline (A staged 1 K-tile ahead, B 2 K-tiles ahead; vmcnt never
// drained to 0 in the main loop except at the final K-tile). Raw s_barrier:
// 2 per K-tile. Per-wave output 128 x BN/4. Bank-conflict-free via the
// verified (row&7)<<4 XOR swizzle + pre-swizzled global source for
// global_load_lds (linear LDS dest).
// ---------------------------------------------------------------------------
template<int BN, bool HAS_BIAS, bool RELU, bool HAS_RES, bool OUT_F32>
__global__ __launch_bounds__(512, 2)
void gemm256(const ushort_t* __restrict__ A, const ushort_t* __restrict__ Bt,
             const float* __restrict__ bias, const float* __restrict__ res,
             void* __restrict__ outp, int M, int N, int K) {
    constexpr int NFR = BN / 64;     // B fragments per wave (4 or 2)
    constexpr int BISS = BN / 64;    // B stage issues per thread (4 or 2)
    __shared__ __align__(16) ushort_t As[2][256 * 64];
    __shared__ __align__(16) ushort_t Bs[2][BN * 64];
    const int t = threadIdx.x;
    const int wave = t >> 6, lane = t & 63;
    const int wm = wave >> 2, wn = wave & 3;
    const int g = lane >> 4, l16 = lane & 15;
    // XCD bijective swizzle (all grids have nwg % 8 == 0)
    int wid = blockIdx.y * gridDim.x + blockIdx.x;
    const int cpx = (gridDim.x * gridDim.y) >> 3;
    wid = (wid & 7) * cpx + (wid >> 3);
    const int m0 = (wid / gridDim.x) * 256;
    const int n0 = (wid % gridDim.x) * BN;
    const int lrow8 = lane >> 3;
    const int srcCol = ((lane & 7) ^ lrow8) * 8;   // pre-swizzled source chunk
    const ushort_t* Abase = A + (size_t)m0 * K + srcCol;
    const ushort_t* Bbase = Bt + (size_t)n0 * K + srcCol;
    const int NKT = K >> 6;

    f32x4 acc[8][NFR] = {};

    auto stageA = [&](int kt, int slot) {
        #pragma unroll
        for (int j = 0; j < 4; j++) {
            const int rowbase = j * 64 + wave * 8;          // wave-uniform
            async_load16(Abase + (size_t)(rowbase + lrow8) * K + kt * 64,
                         &As[slot][rowbase * 64]);
        }
    };
    auto stageB = [&](int kt, int slot) {
        #pragma unroll
        for (int j = 0; j < BISS; j++) {
            const int rowbase = j * 64 + wave * 8;
            async_load16(Bbase + (size_t)(rowbase + lrow8) * K + kt * 64,
                         &Bs[slot][rowbase * 64]);
        }
    };

    // prologue: A(0), B(0) needed at first boundary; B(1) stays in flight
    stageA(0, 0);
    stageB(0, 0);
    stageB(1, 1);

    for (int kt = 0; kt < NKT; ++kt) {
        const int cur = kt & 1;
        // K-tile boundary: wait for A(kt)/B(kt); newest B batch may stay in flight
        if (kt == NKT - 1) {
            asm volatile("s_waitcnt vmcnt(0)" ::: "memory");
        } else if constexpr (BN == 256) {
            asm volatile("s_waitcnt vmcnt(4)" ::: "memory");
        } else {
            asm volatile("s_waitcnt vmcnt(2)" ::: "memory");
        }
        __builtin_amdgcn_s_barrier();

        const ushort_t* as = As[cur];
        const ushort_t* bs = Bs[cur];

        // B fragments for the whole K-tile -> registers (reused by all quadrants)
        bf16x8 bfr[NFR][2];
        #pragma unroll
        for (int nf = 0; nf < NFR; nf++)
            #pragma unroll
            for (int ks = 0; ks < 2; ks++) {
                const int row = wn * (BN / 4) + nf * 16 + l16;
                int a = row * 128 + ks * 64 + 16 * g;
                a ^= (row & 7) << 4;
                bfr[nf][ks] = *(const bf16x8*)((const char*)bs + a);
            }
        // prefetch A of next K-tile into the other slot (dest idle since last barrier)
        if (kt + 1 < NKT) stageA(kt + 1, cur ^ 1);

        #pragma unroll
        for (int q = 0; q < 4; q++) {
            if (q == 2) {
                // all waves have consumed B(kt) into registers -> B slot reusable
                __builtin_amdgcn_s_barrier();
                if (kt + 2 < NKT) stageB(kt + 2, cur);
            }
            bf16x8 af[2][2];
            #pragma unroll
            for (int mi2 = 0; mi2 < 2; mi2++)
                #pragma unroll
                for (int ks = 0; ks < 2; ks++) {
                    const int row = wm * 128 + (q * 2 + mi2) * 16 + l16;
                    int a = row * 128 + ks * 64 + 16 * g;
                    a ^= (row & 7) << 4;
                    af[mi2][ks] = *(const bf16x8*)((const char*)as + a);
                }
            __builtin_amdgcn_s_setprio(1);
            #pragma unroll
            for (int mi2 = 0; mi2 < 2; mi2++)
                #pragma unroll
                for (int nf = 0; nf < NFR; nf++)
                    #pragma unroll
                    for (int ks = 0; ks < 2; ks++)
                        acc[q * 2 + mi2][nf] = __builtin_amdgcn_mfma_f32_16x16x32_bf16(
                            af[mi2][ks], bfr[nf][ks], acc[q * 2 + mi2][nf], 0, 0, 0);
            __builtin_amdgcn_s_setprio(0);
        }
    }

    // epilogue
    const int gr0 = m0 + wm * 128 + g * 4;
    const int gc0 = n0 + wn * (BN / 4) + l16;
    #pragma unroll
    for (int mi = 0; mi < 8; mi++) {
        #pragma unroll
        for (int nf = 0; nf < NFR; nf++) {
            const int col = gc0 + nf * 16;
            float bb = 0.f;
            if constexpr (HAS_BIAS) bb = bias[col];
            #pragma unroll
            for (int r = 0; r < 4; r++) {
                const int row = gr0 + mi * 16 + r;
                float v = acc[mi][nf][r] + bb;
                if constexpr (RELU) v = fmaxf(v, 0.f);
                if constexpr (HAS_RES) v += res[(size_t)row * N + col];
                if constexpr (OUT_F32)
                    ((float*)outp)[(size_t)row * N + col] = v;
                else
                    ((ushort_t*)outp)[(size_t)row * N + col] = f2bf(v);
            }
        }
    }
}

// ---------------------------------------------------------------------------
// Causal flash attention. QBLK=128: 4 waves x 32 q-rows (2 q-col-blocks per
// wave, K/V fragments reused by both -> 1:2 LDS-read:MFMA). KVBLK=64.
// 256-thread blocks, grid (8,64)=512 = exactly 2 independent blocks/CU.
// Pairs (qt, 15-qt): every block exactly 34 kv iterations. exp2-domain
// softmax (log2e folded into Wq). XCD swizzle co-locates each bh's blocks.
// ---------------------------------------------------------------------------
__global__ __launch_bounds__(256)
void attn_kernel(const ushort_t* __restrict__ qkv, ushort_t* __restrict__ out) {
    __shared__ __align__(16) ushort_t Ks[64 * 64];   // linear, XOR-swizzle on read
    __shared__ __align__(16) ushort_t Vt[64 * 64];   // d-major, XOR-swizzled
    __shared__ unsigned int Pw[4][32][35];           // per-wave P words
    const int L = blockIdx.y * gridDim.x + blockIdx.x;   // grid (8,64) -> 512
    const int xcd = L & 7, kk = L >> 3;              // kk 0..63 per XCD
    const int bh = ((kk & 7) << 3) | xcd;            // 8 pair-blocks of bh -> one XCD
    const int pairIdx = kk >> 3;                     // 0..7
    const int b = bh >> 4, h = bh & 15;
    const int t = threadIdx.x, wave = t >> 6, lane = t & 63;
    const int g = lane >> 4, q16 = lane & 15;
    const size_t base = ((size_t)b * NT) * 3072 + h * NHD;
    const ushort_t* qp_base = qkv + base;
    const ushort_t* kb = qkv + base + 1024;
    const ushort_t* vb = qkv + base + 2048;
    // K staging: 2 x global_load_lds per thread; HW dest = base + lane*16
    const int krw = lane >> 3, kck = lane & 7;
    const int ksrc = (kck ^ krw) * 8;                // pre-swizzled source column
    // V staging: thread handles 8 d-values x 2 k
    const int vkp = t >> 3, vdg = t & 7;

    for (int half = 0; half < 2; half++) {
        const int qt = half ? (15 - pairIdx) : pairIdx;
        const int q0 = qt * 128;
        const int wq0 = q0 + wave * 32;
        bf16x8 qf[2][2];
        #pragma unroll
        for (int qb2 = 0; qb2 < 2; qb2++) {
            const ushort_t* qp = qp_base + (size_t)(wq0 + 16 * qb2 + q16) * 3072 + 8 * g;
            qf[qb2][0] = *(const bf16x8*)qp;
            qf[qb2][1] = *(const bf16x8*)(qp + 32);
        }
        f32x4 of[2][4] = {};
        float m_run[2] = {-1.0e30f, -1.0e30f};
        float l_run[2] = {0.f, 0.f};
        const int nkv = 2 * qt + 2;

        for (int kv = 0; kv < nkv; ++kv) {
            __syncthreads();
            // K: two global_load_lds per thread (8KB tile, 32 rows per call)
            #pragma unroll
            for (int c = 0; c < 2; c++) {
                const int rowbase = c * 32 + wave * 8;      // wave-uniform
                async_load16(kb + (size_t)(kv * 64 + rowbase + krw) * 3072 + ksrc,
                             Ks + rowbase * 64);
            }
            // V: register transpose to d-major, XOR-swizzled
            {
                const ushort_t* vp = vb + (size_t)(kv * 64 + 2 * vkp) * 3072 + vdg * 8;
                s16x8 v0 = *(const s16x8*)vp;
                s16x8 v1 = *(const s16x8*)(vp + 3072);
                #pragma unroll
                for (int dd = 0; dd < 8; dd++) {
                    int d = vdg * 8 + dd;
                    unsigned int wv = (unsigned int)(ushort_t)v0[dd] |
                                      ((unsigned int)(ushort_t)v1[dd] << 16);
                    int a = (d << 7) + (vkp << 2);
                    a ^= (((d & 7) ^ ((d >> 3) & 7)) << 4);
                    *(unsigned int*)((char*)Vt + a) = wv;
                }
            }
            __syncthreads();

            const int kbase = kv * 64;
            if (kbase > wq0 + 31) continue;   // wave fully beyond causal reach

            // K fragments: loaded once, shared by both q-blocks
            bf16x8 kf[4][2];
            #pragma unroll
            for (int n = 0; n < 4; n++)
                #pragma unroll
                for (int kd = 0; kd < 2; kd++) {
                    int row = n * 16 + q16;
                    int a = row * 128 + (kd * 64 + 16 * g);
                    a ^= ((row & 7) << 4);
                    kf[n][kd] = *(const bf16x8*)((const char*)Ks + a);
                }

            // S^T = K Q^T for both q-blocks
            f32x4 sf[2][4] = {};
            #pragma unroll
            for (int n = 0; n < 4; n++)
                #pragma unroll
                for (int kd = 0; kd < 2; kd++) {
                    sf[0][n] = __builtin_amdgcn_mfma_f32_16x16x32_bf16(
                        kf[n][kd], qf[0][kd], sf[0][n], 0, 0, 0);
                    sf[1][n] = __builtin_amdgcn_mfma_f32_16x16x32_bf16(
                        kf[n][kd], qf[1][kd], sf[1][n], 0, 0, 0);
                }

            // softmax (exp2 domain) per q-block
            #pragma unroll
            for (int qb2 = 0; qb2 < 2; qb2++) {
                const int wqb = wq0 + 16 * qb2 + q16;
                const bool partial = (kbase + 63 > wq0 + 16 * qb2);
                float p[4][4];
                #pragma unroll
                for (int n = 0; n < 4; n++)
                    #pragma unroll
                    for (int r = 0; r < 4; r++) {
                        float v = sf[qb2][n][r];
                        if (partial) {
                            int kg = kbase + n * 16 + 4 * g + r;
                            if (kg > wqb) v = -1.0e30f;
                        }
                        p[n][r] = v;
                    }
                float mx0 = fmaxf(fmaxf(p[0][0], p[0][1]), fmaxf(p[0][2], p[0][3]));
                float mx1 = fmaxf(fmaxf(p[1][0], p[1][1]), fmaxf(p[1][2], p[1][3]));
                float mx2 = fmaxf(fmaxf(p[2][0], p[2][1]), fmaxf(p[2][2], p[2][3]));
                float mx3 = fmaxf(fmaxf(p[3][0], p[3][1]), fmaxf(p[3][2], p[3][3]));
                float mx = fmaxf(fmaxf(mx0, mx1), fmaxf(mx2, mx3));
                mx = fmaxf(mx, __shfl_xor(mx, 16));
                mx = fmaxf(mx, __shfl_xor(mx, 32));
                // defer-max: 11.5 bits = 8 nats
                if (__any(mx > m_run[qb2] + 11.5f)) {
                    float mn = fmaxf(m_run[qb2], mx);
                    float corr = exp2_fast(m_run[qb2] - mn);
                    m_run[qb2] = mn;
                    l_run[qb2] *= corr;
                    #pragma unroll
                    for (int nf = 0; nf < 4; nf++) {
                        f32x4 o4 = of[qb2][nf];
                        o4[0] *= corr; o4[1] *= corr; o4[2] *= corr; o4[3] *= corr;
                        of[qb2][nf] = o4;
                    }
                }
                float ps = 0.f;
                #pragma unroll
                for (int n = 0; n < 4; n++)
                    #pragma unroll
                    for (int r = 0; r < 4; r++) {
                        p[n][r] = exp2_fast(p[n][r] - m_run[qb2]);
                        ps += p[n][r];
                    }
                ps += __shfl_xor(ps, 16);
                ps += __shfl_xor(ps, 32);
                l_run[qb2] += ps;
                unsigned int* pr = &Pw[wave][16 * qb2 + q16][0];
                #pragma unroll
                for (int n = 0; n < 4; n++) {
                    pr[8 * n + 2 * g + 0] = cvt_pk_bf16(p[n][0], p[n][1]);
                    pr[8 * n + 2 * g + 1] = cvt_pk_bf16(p[n][2], p[n][3]);
                }
            }

            // O^T += V^T P^T ; V fragments shared by both q-blocks
            #pragma unroll
            for (int kbk = 0; kbk < 2; kbk++) {
                bf16x8 pfr[2];
                #pragma unroll
                for (int qb2 = 0; qb2 < 2; qb2++) {
                    const unsigned int* pr = &Pw[wave][16 * qb2 + q16][0];
                    uint4 pu;
                    pu.x = pr[16 * kbk + 4 * g + 0];
                    pu.y = pr[16 * kbk + 4 * g + 1];
                    pu.z = pr[16 * kbk + 4 * g + 2];
                    pu.w = pr[16 * kbk + 4 * g + 3];
                    pfr[qb2] = __builtin_bit_cast(bf16x8, pu);
                }
                #pragma unroll
                for (int nf = 0; nf < 4; nf++) {
                    const int d = nf * 16 + q16;
                    int a = (d << 7) + (kbk * 64 + 16 * g);
                    a ^= (((d & 7) ^ ((d >> 3) & 7)) << 4);
                    bf16x8 vf = *(const bf16x8*)((const char*)Vt + a);
                    of[0][nf] = __builtin_amdgcn_mfma_f32_16x16x32_bf16(
                        vf, pfr[0], of[0][nf], 0, 0, 0);
                    of[1][nf] = __builtin_amdgcn_mfma_f32_16x16x32_bf16(
                        vf, pfr[1], of[1][nf], 0, 0, 0);
                }
            }
        }

        // epilogue: of[qb][nf][r] = O[q][d = nf*16 + 4g + r]
        #pragma unroll
        for (int qb2 = 0; qb2 < 2; qb2++) {
            float rl = 1.f / l_run[qb2];
            const size_t orow = (size_t)b * NT + q0 + wave * 32 + 16 * qb2 + q16;
            #pragma unroll
            for (int nf = 0; nf < 4; nf++) {
                ushort4 o4;
                o4.x = f2bf(of[qb2][nf][0] * rl);
                o4.y = f2bf(of[qb2][nf][1] * rl);
                o4.z = f2bf(of[qb2][nf][2] * rl);
                o4.w = f2bf(of[qb2][nf][3] * rl);
                *(ushort4*)(out + orow * ND + h * NHD + nf * 16 + 4 * g) = o4;
            }
        }
    }
}

// ---------------------------------------------------------------------------
extern "C" void kernel_launch(void* const* d_in, const int* in_sizes, int n_in,
                              void* d_out, int out_size, void* d_ws, size_t ws_size,
                              hipStream_t stream) {
    const float* x     = (const float*)d_in[0];
    const float* ln1_g = (const float*)d_in[1];
    const float* ln1_b = (const float*)d_in[2];
    const float* ln2_g = (const float*)d_in[3];
    const float* ln2_b = (const float*)d_in[4];
    const float* Wq    = (const float*)d_in[5];
    const float* Wk    = (const float*)d_in[6];
    const float* Wv    = (const float*)d_in[7];
    const float* Wo    = (const float*)d_in[8];
    const float* bo    = (const float*)d_in[9];
    const float* W1    = (const float*)d_in[10];
    const float* b1    = (const float*)d_in[11];
    const float* W2    = (const float*)d_in[12];
    const float* b2    = (const float*)d_in[13];
    float* outp = (float*)d_out;

    char* w = (char*)d_ws;
    ushort_t* Wqkv_t = (ushort_t*)(w);                    // 6 MiB  (3072x1024)
    ushort_t* Wo_t   = (ushort_t*)(w + 6291456);          // 2 MiB  (1024x1024)
    ushort_t* W1_t   = (ushort_t*)(w + 8388608);          // 8 MiB  (4096x1024)
    ushort_t* W2_t   = (ushort_t*)(w + 16777216);         // 8 MiB  (1024x4096)
    ushort_t* xn     = (ushort_t*)(w + 25165824);         // 16 MiB (8192x1024), also hn
    ushort_t* qkv    = (ushort_t*)(w + 41943040);         // 48 MiB (8192x3072)
    ushort_t* attn_o = qkv + (size_t)MTOK * 3072;         // 16 MiB (8192x1024)
    ushort_t* ff1    = qkv;                               // 64 MiB (8192x4096) reuse
    float*    hbuf   = (float*)(w + 41943040 + 67108864); // 32 MiB (8192x1024 f32)

    dim3 tb(32, 8);
    transpose_qkv_to_bf16<<<dim3(2, 32, 48), tb, 0, stream>>>(Wq, Wk, Wv, Wqkv_t);
    transpose_to_bf16<<<dim3(32, 32), tb, 0, stream>>>(Wo, Wo_t, 1024, 1024);
    transpose_to_bf16<<<dim3(128, 32), tb, 0, stream>>>(W1, W1_t, 1024, 4096);
    transpose_to_bf16<<<dim3(32, 128), tb, 0, stream>>>(W2, W2_t, 4096, 1024);

    layernorm_to_bf16<<<MTOK, 256, 0, stream>>>(x, ln1_g, ln1_b, xn);

    // QKV: M=8192, N=3072, K=1024 -> grid 24x32 = 768 blocks (3 exact CU rounds)
    gemm256<128, false, false, false, false><<<dim3(24, 32), 512, 0, stream>>>(
        xn, Wqkv_t, nullptr, nullptr, qkv, MTOK, 3072, 1024);

    attn_kernel<<<dim3(8, 64), 256, 0, stream>>>(qkv, attn_o);

    // Wo: N=1024, K=1024 -> grid 8x32 = 256 blocks (1 exact round)
    gemm256<128, true, false, true, true><<<dim3(8, 32), 512, 0, stream>>>(
        attn_o, Wo_t, bo, x, hbuf, MTOK, 1024, 1024);

    layernorm_to_bf16<<<MTOK, 256, 0, stream>>>(hbuf, ln2_g, ln2_b, xn);

    // FFN1: N=4096, K=1024 -> grid 16x32 = 512 blocks (2 exact rounds)
    gemm256<256, true, true, false, false><<<dim3(16, 32), 512, 0, stream>>>(
        xn, W1_t, b1, nullptr, ff1, MTOK, NF, 1024);

    // FFN2: N=1024, K=4096 -> grid 8x32 = 256 blocks (1 exact round)
    gemm256<128, true, false, true, true><<<dim3(8, 32), 512, 0, stream>>>(
        ff1, W2_t, b2, hbuf, outp, MTOK, 1024, NF);
}